// Round 1
// baseline (472.670 us; speedup 1.0000x reference)
//
#include <hip/hip_runtime.h>
#include <math.h>

#define HEADS 4
#define CH 64
#define HID 256
#define IN_DIM 768
#define NEG_SLOPE 0.2f

// ---------------------------------------------------------------------------
// GEMM: C[M,256] = A[M,K] x B[K,256]   (fp32, tiled, BM=128 BN=64 BK=16)
// ---------------------------------------------------------------------------
#define BM 128
#define BN 64
#define BK 16

__global__ __launch_bounds__(256) void gemm_kernel(
    const float* __restrict__ A, const float* __restrict__ B,
    float* __restrict__ C, int M, int K) {
  __shared__ float As[BK][132];   // [k][row], padded stride 132 (bank spread, 16B aligned)
  __shared__ float Bs[BK][BN];    // [k][col]

  const int t = threadIdx.x;
  const int tx = t & 15;          // 16 col-groups * 4 cols
  const int ty = t >> 4;          // 16 row-groups * 8 rows
  const int row0 = blockIdx.x * BM;
  const int col0 = blockIdx.y * BN;

  float c[8][4];
#pragma unroll
  for (int i = 0; i < 8; ++i)
#pragma unroll
    for (int j = 0; j < 4; ++j) c[i][j] = 0.f;

  for (int k0 = 0; k0 < K; k0 += BK) {
    // ---- load A tile: 128 rows x 16 k, transposed into As[k][row]
#pragma unroll
    for (int r = 0; r < 2; ++r) {
      const int row = (t >> 2) + r * 64;      // 0..127
      const int kq  = (t & 3) * 4;            // 0,4,8,12
      const int grow = row0 + row;
      float4 av = make_float4(0.f, 0.f, 0.f, 0.f);
      if (grow < M)
        av = *reinterpret_cast<const float4*>(&A[(size_t)grow * K + k0 + kq]);
      As[kq + 0][row] = av.x;
      As[kq + 1][row] = av.y;
      As[kq + 2][row] = av.z;
      As[kq + 3][row] = av.w;
    }
    // ---- load B tile: 16 k x 64 cols
    {
      const int kk = t >> 4;            // 0..15
      const int cc = (t & 15) * 4;      // 0..60
      float4 bv = *reinterpret_cast<const float4*>(
          &B[(size_t)(k0 + kk) * HID + col0 + cc]);
      *reinterpret_cast<float4*>(&Bs[kk][cc]) = bv;
    }
    __syncthreads();

#pragma unroll
    for (int k = 0; k < BK; ++k) {
      const float4 a0 = *reinterpret_cast<const float4*>(&As[k][ty * 8]);
      const float4 a1 = *reinterpret_cast<const float4*>(&As[k][ty * 8 + 4]);
      const float4 b  = *reinterpret_cast<const float4*>(&Bs[k][tx * 4]);
      const float ar[8] = {a0.x, a0.y, a0.z, a0.w, a1.x, a1.y, a1.z, a1.w};
      const float br[4] = {b.x, b.y, b.z, b.w};
#pragma unroll
      for (int i = 0; i < 8; ++i)
#pragma unroll
        for (int j = 0; j < 4; ++j)
          c[i][j] = fmaf(ar[i], br[j], c[i][j]);
    }
    __syncthreads();
  }

#pragma unroll
  for (int i = 0; i < 8; ++i) {
    const int grow = row0 + ty * 8 + i;
    if (grow < M) {
      float4 v = make_float4(c[i][0], c[i][1], c[i][2], c[i][3]);
      *reinterpret_cast<float4*>(&C[(size_t)grow * HID + col0 + tx * 4]) = v;
    }
  }
}

// ---------------------------------------------------------------------------
// Attention logits: al_s[n,h] = <h[n,h,:], a_src[h,:]>, same for al_d
// one block per node, 4 waves = 4 heads
// ---------------------------------------------------------------------------
__global__ __launch_bounds__(256) void alpha_kernel(
    const float* __restrict__ h, const float* __restrict__ a_src,
    const float* __restrict__ a_dst, float* __restrict__ al_s,
    float* __restrict__ al_d, int n) {
  const int node = blockIdx.x;
  const int hd = threadIdx.x >> 6;
  const int lane = threadIdx.x & 63;
  const float hv = h[(size_t)node * HID + hd * CH + lane];
  float vs = hv * a_src[hd * CH + lane];
  float vd = hv * a_dst[hd * CH + lane];
#pragma unroll
  for (int m = 32; m >= 1; m >>= 1) {
    vs += __shfl_xor(vs, m);
    vd += __shfl_xor(vd, m);
  }
  if (lane == 0) {
    al_s[node * HEADS + hd] = vs;
    al_d[node * HEADS + hd] = vd;
  }
}

// ---------------------------------------------------------------------------
// CSR build: histogram -> scan -> scatter (stores src per sorted edge)
// ---------------------------------------------------------------------------
__global__ void hist_kernel(const int* __restrict__ edge_dst, int* __restrict__ deg,
                            int E, int ET) {
  const int e = blockIdx.x * blockDim.x + threadIdx.x;
  if (e < ET) {
    const int d = (e < E) ? edge_dst[e] : (e - E);
    atomicAdd(&deg[d], 1);
  }
}

__global__ __launch_bounds__(1024) void scan_kernel(const int* __restrict__ deg,
                                                    int* __restrict__ row_ptr, int n) {
  __shared__ int sm[1024];
  __shared__ int carry_s;
  const int t = threadIdx.x;
  if (t == 0) {
    carry_s = 0;
    row_ptr[0] = 0;
  }
  __syncthreads();
  for (int base = 0; base < n; base += 1024) {
    const int idx = base + t;
    int v = (idx < n) ? deg[idx] : 0;
    sm[t] = v;
    __syncthreads();
    for (int off = 1; off < 1024; off <<= 1) {
      int add = (t >= off) ? sm[t - off] : 0;
      __syncthreads();
      sm[t] += add;
      __syncthreads();
    }
    const int carry = carry_s;
    if (idx < n) row_ptr[idx + 1] = carry + sm[t];
    __syncthreads();
    if (t == 1023) carry_s = carry + sm[1023];
    __syncthreads();
  }
}

__global__ void scatter_kernel(const int* __restrict__ edge_src,
                               const int* __restrict__ edge_dst,
                               const int* __restrict__ row_ptr,
                               int* __restrict__ cursor,
                               int* __restrict__ ssrc, int E, int ET) {
  const int e = blockIdx.x * blockDim.x + threadIdx.x;
  if (e < ET) {
    int d, s;
    if (e < E) {
      d = edge_dst[e];
      s = edge_src[e];
    } else {
      d = s = e - E;
    }
    const int pos = atomicAdd(&cursor[d], 1);
    ssrc[row_ptr[d] + pos] = s;
  }
}

// ---------------------------------------------------------------------------
// Segment softmax + aggregate (online), one block per dst node, wave = head
// ---------------------------------------------------------------------------
__global__ __launch_bounds__(256) void agg_kernel(
    const float* __restrict__ h, const float* __restrict__ al_s,
    const float* __restrict__ al_d, const int* __restrict__ row_ptr,
    const int* __restrict__ ssrc, const float* __restrict__ bias,
    float* __restrict__ out, int n) {
  const int d = blockIdx.x;
  const int hd = threadIdx.x >> 6;
  const int lane = threadIdx.x & 63;
  const int start = row_ptr[d];
  const int end = row_ptr[d + 1];
  const float ald = al_d[d * HEADS + hd];

  float M = -INFINITY, S = 0.f, acc = 0.f;
  for (int i = start; i < end; ++i) {
    const int s = ssrc[i];
    float e = al_s[s * HEADS + hd] + ald;
    e = (e > 0.f) ? e : NEG_SLOPE * e;
    const float hv = h[(size_t)s * HID + hd * CH + lane];
    const float nM = fmaxf(M, e);
    const float scale = expf(M - nM);   // first iter: exp(-inf)=0
    const float p = expf(e - nM);
    S = S * scale + p;
    acc = acc * scale + p * hv;
    M = nM;
  }
  out[(size_t)d * HID + hd * CH + lane] = acc / (S + 1e-16f) + bias[hd * CH + lane];
}

// ---------------------------------------------------------------------------
extern "C" void kernel_launch(void* const* d_in, const int* in_sizes, int n_in,
                              void* d_out, int out_size, void* d_ws, size_t ws_size,
                              hipStream_t stream) {
  const float* x    = (const float*)d_in[0];
  const int* esrc   = (const int*)d_in[1];
  const int* edst   = (const int*)d_in[2];
  const float* W1   = (const float*)d_in[3];
  const float* a1s  = (const float*)d_in[4];
  const float* a1d  = (const float*)d_in[5];
  const float* b1   = (const float*)d_in[6];
  const float* W2   = (const float*)d_in[7];
  const float* a2s  = (const float*)d_in[8];
  const float* a2d  = (const float*)d_in[9];
  const float* b2   = (const float*)d_in[10];
  float* out = (float*)d_out;

  const int N = in_sizes[0] / IN_DIM;   // 20000
  const int E = in_sizes[1];            // 320000
  const int ET = E + N;                 // + self loops

  char* ws = (char*)d_ws;
  float* h = (float*)ws;       ws += (size_t)N * HID * sizeof(float);
  float* al_s = (float*)ws;    ws += (size_t)N * HEADS * sizeof(float);
  float* al_d = (float*)ws;    ws += (size_t)N * HEADS * sizeof(float);
  int* row_ptr = (int*)ws;     ws += (size_t)(N + 1) * sizeof(int);
  int* deg = (int*)ws;         ws += (size_t)N * sizeof(int);
  int* cursor = (int*)ws;      ws += (size_t)N * sizeof(int);
  int* ssrc = (int*)ws;        ws += (size_t)ET * sizeof(int);

  // x1 (layer-1 output) lives in d_out between the two layers.
  float* x1 = out;

  hipMemsetAsync(deg, 0, (size_t)N * sizeof(int), stream);
  hipMemsetAsync(cursor, 0, (size_t)N * sizeof(int), stream);

  const int thr = 256;
  hist_kernel<<<(ET + thr - 1) / thr, thr, 0, stream>>>(edst, deg, E, ET);
  scan_kernel<<<1, 1024, 0, stream>>>(deg, row_ptr, N);
  scatter_kernel<<<(ET + thr - 1) / thr, thr, 0, stream>>>(esrc, edst, row_ptr,
                                                           cursor, ssrc, E, ET);

  dim3 ggrid((N + BM - 1) / BM, HID / BN);
  // ---- layer 1
  gemm_kernel<<<ggrid, 256, 0, stream>>>(x, W1, h, N, IN_DIM);
  alpha_kernel<<<N, 256, 0, stream>>>(h, a1s, a1d, al_s, al_d, N);
  agg_kernel<<<N, 256, 0, stream>>>(h, al_s, al_d, row_ptr, ssrc, b1, x1, N);
  // ---- layer 2
  gemm_kernel<<<ggrid, 256, 0, stream>>>(x1, W2, h, N, HID);
  alpha_kernel<<<N, 256, 0, stream>>>(h, a2s, a2d, al_s, al_d, N);
  agg_kernel<<<N, 256, 0, stream>>>(h, al_s, al_d, row_ptr, ssrc, b2, out, N);
}

// Round 2
// 330.112 us; speedup vs baseline: 1.4319x; 1.4319x over previous
//
#include <hip/hip_runtime.h>
#include <math.h>

#define HEADS 4
#define CH 64
#define HID 256
#define IN_DIM 768
#define NEG_SLOPE 0.2f

typedef _Float16 f16x8 __attribute__((ext_vector_type(8)));
typedef float f32x4 __attribute__((ext_vector_type(4)));

// ---------------------------------------------------------------------------
// W [K][256] fp32 -> Wt [256][K] fp16  (coalesced read, scattered 2B write; tiny)
// ---------------------------------------------------------------------------
__global__ void wconv_kernel(const float* __restrict__ W, _Float16* __restrict__ Wt,
                             int K) {
  const int idx = blockIdx.x * blockDim.x + threadIdx.x;  // over k*256+n
  if (idx < K * HID) {
    const int k = idx >> 8;
    const int n = idx & 255;
    Wt[(size_t)n * K + k] = (_Float16)W[idx];
  }
}

// ---------------------------------------------------------------------------
// GEMM: C[M,256] = A[M,K] (fp32) x Bt[256,K]^T (fp16)  via mfma_f32_16x16x32_f16
// Block 256 thr = 4 waves (2x2), tile 128x128, BK=32. LDS stride 40 fp16.
// ---------------------------------------------------------------------------
#define BM 128
#define BN 128
#define BK 32
#define LDH 40

__global__ __launch_bounds__(256) void gemm_f16(
    const float* __restrict__ A, const _Float16* __restrict__ Bt,
    float* __restrict__ C, int M, int K) {
  __shared__ _Float16 As[BM * LDH];
  __shared__ _Float16 Bs[BN * LDH];

  const int t = threadIdx.x;
  const int lane = t & 63;
  const int wid = t >> 6;
  const int wm = wid & 1;        // wave row (0..1) -> 64 rows
  const int wn = wid >> 1;       // wave col (0..1) -> 64 cols
  const int row0 = blockIdx.x * BM;
  const int col0 = blockIdx.y * BN;

  f32x4 acc[4][4] = {};

  const int srow = t >> 1;           // 0..127
  const int sks = (t & 1) * 16;      // 0 or 16

  const int kb = (lane >> 4) * 8;    // fragment k-base
  const int rl = lane & 15;          // fragment row/col within 16

  for (int k0 = 0; k0 < K; k0 += BK) {
    // ---- stage A tile: 128 rows x 32 k, fp32 -> fp16
    {
      const int grow = row0 + srow;
      float4 a0{}, a1{}, a2{}, a3{};
      if (grow < M) {
        const float* p = &A[(size_t)grow * K + k0 + sks];
        a0 = *reinterpret_cast<const float4*>(p + 0);
        a1 = *reinterpret_cast<const float4*>(p + 4);
        a2 = *reinterpret_cast<const float4*>(p + 8);
        a3 = *reinterpret_cast<const float4*>(p + 12);
      }
      f16x8 p0 = {(_Float16)a0.x, (_Float16)a0.y, (_Float16)a0.z, (_Float16)a0.w,
                  (_Float16)a1.x, (_Float16)a1.y, (_Float16)a1.z, (_Float16)a1.w};
      f16x8 p1 = {(_Float16)a2.x, (_Float16)a2.y, (_Float16)a2.z, (_Float16)a2.w,
                  (_Float16)a3.x, (_Float16)a3.y, (_Float16)a3.z, (_Float16)a3.w};
      *reinterpret_cast<f16x8*>(&As[srow * LDH + sks]) = p0;
      *reinterpret_cast<f16x8*>(&As[srow * LDH + sks + 8]) = p1;
    }
    // ---- stage B tile from Bt[col][k] fp16 (already transposed)
    {
      const _Float16* p = &Bt[(size_t)(col0 + srow) * K + k0 + sks];
      f16x8 b0 = *reinterpret_cast<const f16x8*>(p);
      f16x8 b1 = *reinterpret_cast<const f16x8*>(p + 8);
      *reinterpret_cast<f16x8*>(&Bs[srow * LDH + sks]) = b0;
      *reinterpret_cast<f16x8*>(&Bs[srow * LDH + sks + 8]) = b1;
    }
    __syncthreads();

    f16x8 af[4], bf[4];
#pragma unroll
    for (int m = 0; m < 4; ++m)
      af[m] = *reinterpret_cast<const f16x8*>(&As[(wm * 64 + m * 16 + rl) * LDH + kb]);
#pragma unroll
    for (int n = 0; n < 4; ++n)
      bf[n] = *reinterpret_cast<const f16x8*>(&Bs[(wn * 64 + n * 16 + rl) * LDH + kb]);
#pragma unroll
    for (int m = 0; m < 4; ++m)
#pragma unroll
      for (int n = 0; n < 4; ++n)
        acc[m][n] = __builtin_amdgcn_mfma_f32_16x16x32_f16(af[m], bf[n], acc[m][n],
                                                           0, 0, 0);
    __syncthreads();
  }

  // ---- epilogue: C[row][col], row=(lane>>4)*4+r, col=lane&15 within frag
  const int rq = lane >> 4;
#pragma unroll
  for (int m = 0; m < 4; ++m) {
    const int gr0 = row0 + wm * 64 + m * 16 + rq * 4;
#pragma unroll
    for (int n = 0; n < 4; ++n) {
      const int gc = col0 + wn * 64 + n * 16 + rl;
#pragma unroll
      for (int r = 0; r < 4; ++r) {
        const int gr = gr0 + r;
        if (gr < M) C[(size_t)gr * HID + gc] = acc[m][n][r];
      }
    }
  }
}

// ---------------------------------------------------------------------------
// Attention logits: al_s[n,h] = <h[n,h,:], a_src[h,:]>, same for al_d
// ---------------------------------------------------------------------------
__global__ __launch_bounds__(256) void alpha_kernel(
    const float* __restrict__ h, const float* __restrict__ a_src,
    const float* __restrict__ a_dst, float* __restrict__ al_s,
    float* __restrict__ al_d, int n) {
  const int node = blockIdx.x;
  const int hd = threadIdx.x >> 6;
  const int lane = threadIdx.x & 63;
  const float hv = h[(size_t)node * HID + hd * CH + lane];
  float vs = hv * a_src[hd * CH + lane];
  float vd = hv * a_dst[hd * CH + lane];
#pragma unroll
  for (int m = 32; m >= 1; m >>= 1) {
    vs += __shfl_xor(vs, m);
    vd += __shfl_xor(vd, m);
  }
  if (lane == 0) {
    al_s[node * HEADS + hd] = vs;
    al_d[node * HEADS + hd] = vd;
  }
}

// ---------------------------------------------------------------------------
// CSR build
// ---------------------------------------------------------------------------
__global__ void hist_kernel(const int* __restrict__ edge_dst, int* __restrict__ deg,
                            int E, int ET) {
  const int e = blockIdx.x * blockDim.x + threadIdx.x;
  if (e < ET) {
    const int d = (e < E) ? edge_dst[e] : (e - E);
    atomicAdd(&deg[d], 1);
  }
}

__global__ __launch_bounds__(1024) void scan_kernel(const int* __restrict__ deg,
                                                    int* __restrict__ row_ptr, int n) {
  __shared__ int wsum[16];
  __shared__ int carry_s;
  const int t = threadIdx.x, lane = t & 63, w = t >> 6;
  if (t == 0) {
    carry_s = 0;
    row_ptr[0] = 0;
  }
  __syncthreads();
  for (int base = 0; base < n; base += 1024) {
    const int idx = base + t;
    int x = (idx < n) ? deg[idx] : 0;
#pragma unroll
    for (int off = 1; off < 64; off <<= 1) {
      int y = __shfl_up(x, off);
      if (lane >= off) x += y;
    }
    if (lane == 63) wsum[w] = x;
    __syncthreads();
    if (w == 0) {
      int s = (lane < 16) ? wsum[lane] : 0;
#pragma unroll
      for (int off = 1; off < 16; off <<= 1) {
        int y = __shfl_up(s, off);
        if (lane >= off) s += y;
      }
      if (lane < 16) wsum[lane] = s;
    }
    __syncthreads();
    const int woff = (w > 0) ? wsum[w - 1] : 0;
    const int incl = carry_s + woff + x;
    if (idx < n) row_ptr[idx + 1] = incl;
    __syncthreads();
    if (t == 1023) carry_s = incl;
    __syncthreads();
  }
}

__global__ void scatter_kernel(const int* __restrict__ edge_src,
                               const int* __restrict__ edge_dst,
                               const int* __restrict__ row_ptr,
                               int* __restrict__ cursor,
                               int* __restrict__ ssrc, int E, int ET) {
  const int e = blockIdx.x * blockDim.x + threadIdx.x;
  if (e < ET) {
    int d, s;
    if (e < E) {
      d = edge_dst[e];
      s = edge_src[e];
    } else {
      d = s = e - E;
    }
    const int pos = atomicAdd(&cursor[d], 1);
    ssrc[row_ptr[d] + pos] = s;
  }
}

// ---------------------------------------------------------------------------
// Segment softmax + aggregate (online), block per dst node, wave = head.
// Prefetch next (ssrc, al_s) to break the serial dependent-load chain.
// ---------------------------------------------------------------------------
__global__ __launch_bounds__(256) void agg_kernel(
    const float* __restrict__ h, const float* __restrict__ al_s,
    const float* __restrict__ al_d, const int* __restrict__ row_ptr,
    const int* __restrict__ ssrc, const float* __restrict__ bias,
    float* __restrict__ out, int n) {
  const int d = blockIdx.x;
  const int hd = threadIdx.x >> 6;
  const int lane = threadIdx.x & 63;
  const int start = row_ptr[d];
  const int end = row_ptr[d + 1];
  const float ald = al_d[d * HEADS + hd];

  float M = -INFINITY, S = 0.f, acc = 0.f;
  int sN = (start < end) ? ssrc[start] : 0;
  float aN = (start < end) ? al_s[sN * HEADS + hd] : 0.f;
  for (int i = start; i < end; ++i) {
    const int s = sN;
    const float araw = aN;
    const float hv = h[(size_t)s * HID + hd * CH + lane];  // issue early
    if (i + 1 < end) {
      sN = ssrc[i + 1];
      aN = al_s[sN * HEADS + hd];
    }
    float e = araw + ald;
    e = (e > 0.f) ? e : NEG_SLOPE * e;
    const float nM = fmaxf(M, e);
    const float scale = __expf(M - nM);
    const float p = __expf(e - nM);
    S = S * scale + p;
    acc = acc * scale + p * hv;
    M = nM;
  }
  out[(size_t)d * HID + hd * CH + lane] = acc / (S + 1e-16f) + bias[hd * CH + lane];
}

// ---------------------------------------------------------------------------
extern "C" void kernel_launch(void* const* d_in, const int* in_sizes, int n_in,
                              void* d_out, int out_size, void* d_ws, size_t ws_size,
                              hipStream_t stream) {
  const float* x   = (const float*)d_in[0];
  const int* esrc  = (const int*)d_in[1];
  const int* edst  = (const int*)d_in[2];
  const float* W1  = (const float*)d_in[3];
  const float* a1s = (const float*)d_in[4];
  const float* a1d = (const float*)d_in[5];
  const float* b1  = (const float*)d_in[6];
  const float* W2  = (const float*)d_in[7];
  const float* a2s = (const float*)d_in[8];
  const float* a2d = (const float*)d_in[9];
  const float* b2  = (const float*)d_in[10];
  float* out = (float*)d_out;

  const int N = in_sizes[0] / IN_DIM;  // 20000
  const int E = in_sizes[1];           // 320000
  const int ET = E + N;

  char* ws = (char*)d_ws;
  float* h = (float*)ws;        ws += (size_t)N * HID * sizeof(float);
  float* al_s = (float*)ws;     ws += (size_t)N * HEADS * sizeof(float);
  float* al_d = (float*)ws;     ws += (size_t)N * HEADS * sizeof(float);
  int* row_ptr = (int*)ws;      ws += (size_t)(N + 1) * sizeof(int);
  int* deg = (int*)ws;          ws += (size_t)N * sizeof(int);
  int* cursor = (int*)ws;       ws += (size_t)N * sizeof(int);
  int* ssrc = (int*)ws;         ws += (size_t)ET * sizeof(int);
  ws = (char*)(((size_t)ws + 15) & ~(size_t)15);
  _Float16* W1t = (_Float16*)ws; ws += (size_t)HID * IN_DIM * sizeof(_Float16);
  _Float16* W2t = (_Float16*)ws; ws += (size_t)HID * HID * sizeof(_Float16);

  float* x1 = out;  // layer-1 output lives in d_out

  hipMemsetAsync(deg, 0, (size_t)N * sizeof(int), stream);
  hipMemsetAsync(cursor, 0, (size_t)N * sizeof(int), stream);

  const int thr = 256;
  wconv_kernel<<<(IN_DIM * HID + thr - 1) / thr, thr, 0, stream>>>(W1, W1t, IN_DIM);
  wconv_kernel<<<(HID * HID + thr - 1) / thr, thr, 0, stream>>>(W2, W2t, HID);

  hist_kernel<<<(ET + thr - 1) / thr, thr, 0, stream>>>(edst, deg, E, ET);
  scan_kernel<<<1, 1024, 0, stream>>>(deg, row_ptr, N);
  scatter_kernel<<<(ET + thr - 1) / thr, thr, 0, stream>>>(esrc, edst, row_ptr,
                                                           cursor, ssrc, E, ET);

  dim3 ggrid((N + BM - 1) / BM, HID / BN);
  // ---- layer 1
  gemm_f16<<<ggrid, 256, 0, stream>>>(x, W1t, h, N, IN_DIM);
  alpha_kernel<<<N, 256, 0, stream>>>(h, a1s, a1d, al_s, al_d, N);
  agg_kernel<<<N, 256, 0, stream>>>(h, al_s, al_d, row_ptr, ssrc, b1, x1, N);
  // ---- layer 2
  gemm_f16<<<ggrid, 256, 0, stream>>>(x1, W2t, h, N, HID);
  alpha_kernel<<<N, 256, 0, stream>>>(h, a2s, a2d, al_s, al_d, N);
  agg_kernel<<<N, 256, 0, stream>>>(h, al_s, al_d, row_ptr, ssrc, b2, out, N);
}

// Round 3
// 248.221 us; speedup vs baseline: 1.9042x; 1.3299x over previous
//
#include <hip/hip_runtime.h>
#include <math.h>

#define HEADS 4
#define CH 64
#define HID 256
#define IN_DIM 768
#define NEG_SLOPE 0.2f

typedef _Float16 f16x8 __attribute__((ext_vector_type(8)));
typedef _Float16 f16x2 __attribute__((ext_vector_type(2)));
typedef float f32x4 __attribute__((ext_vector_type(4)));

// ---------------------------------------------------------------------------
// W [K][256] fp32 -> Wt [256][K] fp16
// ---------------------------------------------------------------------------
__global__ void wconv_kernel(const float* __restrict__ W, _Float16* __restrict__ Wt,
                             int K) {
  const int idx = blockIdx.x * blockDim.x + threadIdx.x;
  if (idx < K * HID) {
    const int k = idx >> 8;
    const int n = idx & 255;
    Wt[(size_t)n * K + k] = (_Float16)W[idx];
  }
}

// ---------------------------------------------------------------------------
// GEMM: C16[M,256] = A[M,K] x Bt[256,K]^T  via mfma_f32_16x16x32_f16
// A fp32 (layer1) or fp16 (layer2). C written fp16. 256 thr, 128x128, BK=32.
// ---------------------------------------------------------------------------
#define BM 128
#define BN 128
#define BK 32
#define LDH 40

template <bool AF16>
__global__ __launch_bounds__(256) void gemm_f16(
    const void* __restrict__ Av, const _Float16* __restrict__ Bt,
    _Float16* __restrict__ C, int M, int K) {
  __shared__ _Float16 As[BM * LDH];
  __shared__ _Float16 Bs[BN * LDH];

  const int t = threadIdx.x;
  const int lane = t & 63;
  const int wid = t >> 6;
  const int wm = wid & 1;
  const int wn = wid >> 1;
  const int row0 = blockIdx.x * BM;
  const int col0 = blockIdx.y * BN;

  f32x4 acc[4][4] = {};

  const int srow = t >> 1;        // 0..127
  const int sks = (t & 1) * 16;   // 0 or 16

  const int kb = (lane >> 4) * 8;
  const int rl = lane & 15;

  for (int k0 = 0; k0 < K; k0 += BK) {
    // ---- stage A tile
    {
      const int grow = row0 + srow;
      if (AF16) {
        const _Float16* A16 = (const _Float16*)Av;
        f16x8 p0 = {}, p1 = {};
        if (grow < M) {
          const _Float16* p = &A16[(size_t)grow * K + k0 + sks];
          p0 = *reinterpret_cast<const f16x8*>(p);
          p1 = *reinterpret_cast<const f16x8*>(p + 8);
        }
        *reinterpret_cast<f16x8*>(&As[srow * LDH + sks]) = p0;
        *reinterpret_cast<f16x8*>(&As[srow * LDH + sks + 8]) = p1;
      } else {
        const float* A32 = (const float*)Av;
        float4 a0{}, a1{}, a2{}, a3{};
        if (grow < M) {
          const float* p = &A32[(size_t)grow * K + k0 + sks];
          a0 = *reinterpret_cast<const float4*>(p + 0);
          a1 = *reinterpret_cast<const float4*>(p + 4);
          a2 = *reinterpret_cast<const float4*>(p + 8);
          a3 = *reinterpret_cast<const float4*>(p + 12);
        }
        f16x8 p0 = {(_Float16)a0.x, (_Float16)a0.y, (_Float16)a0.z, (_Float16)a0.w,
                    (_Float16)a1.x, (_Float16)a1.y, (_Float16)a1.z, (_Float16)a1.w};
        f16x8 p1 = {(_Float16)a2.x, (_Float16)a2.y, (_Float16)a2.z, (_Float16)a2.w,
                    (_Float16)a3.x, (_Float16)a3.y, (_Float16)a3.z, (_Float16)a3.w};
        *reinterpret_cast<f16x8*>(&As[srow * LDH + sks]) = p0;
        *reinterpret_cast<f16x8*>(&As[srow * LDH + sks + 8]) = p1;
      }
    }
    // ---- stage B tile
    {
      const _Float16* p = &Bt[(size_t)(col0 + srow) * K + k0 + sks];
      f16x8 b0 = *reinterpret_cast<const f16x8*>(p);
      f16x8 b1 = *reinterpret_cast<const f16x8*>(p + 8);
      *reinterpret_cast<f16x8*>(&Bs[srow * LDH + sks]) = b0;
      *reinterpret_cast<f16x8*>(&Bs[srow * LDH + sks + 8]) = b1;
    }
    __syncthreads();

    f16x8 af[4], bf[4];
#pragma unroll
    for (int m = 0; m < 4; ++m)
      af[m] = *reinterpret_cast<const f16x8*>(&As[(wm * 64 + m * 16 + rl) * LDH + kb]);
#pragma unroll
    for (int n = 0; n < 4; ++n)
      bf[n] = *reinterpret_cast<const f16x8*>(&Bs[(wn * 64 + n * 16 + rl) * LDH + kb]);
#pragma unroll
    for (int m = 0; m < 4; ++m)
#pragma unroll
      for (int n = 0; n < 4; ++n)
        acc[m][n] = __builtin_amdgcn_mfma_f32_16x16x32_f16(af[m], bf[n], acc[m][n],
                                                           0, 0, 0);
    __syncthreads();
  }

  const int rq = lane >> 4;
#pragma unroll
  for (int m = 0; m < 4; ++m) {
    const int gr0 = row0 + wm * 64 + m * 16 + rq * 4;
#pragma unroll
    for (int n = 0; n < 4; ++n) {
      const int gc = col0 + wn * 64 + n * 16 + rl;
#pragma unroll
      for (int r = 0; r < 4; ++r) {
        const int gr = gr0 + r;
        if (gr < M) C[(size_t)gr * HID + gc] = (_Float16)acc[m][n][r];
      }
    }
  }
}

// ---------------------------------------------------------------------------
// Attention logits from h16
// ---------------------------------------------------------------------------
__global__ __launch_bounds__(256) void alpha_kernel(
    const _Float16* __restrict__ h16, const float* __restrict__ a_src,
    const float* __restrict__ a_dst, float* __restrict__ al_s4,
    float* __restrict__ al_d4, int n) {
  const int node = blockIdx.x;
  const int hd = threadIdx.x >> 6;
  const int lane = threadIdx.x & 63;
  const float hv = (float)h16[(size_t)node * HID + hd * CH + lane];
  float vs = hv * a_src[hd * CH + lane];
  float vd = hv * a_dst[hd * CH + lane];
#pragma unroll
  for (int m = 32; m >= 1; m >>= 1) {
    vs += __shfl_xor(vs, m);
    vd += __shfl_xor(vd, m);
  }
  if (lane == 0) {
    al_s4[node * HEADS + hd] = vs;
    al_d4[node * HEADS + hd] = vd;
  }
}

// ---------------------------------------------------------------------------
// CSR build
// ---------------------------------------------------------------------------
__global__ void hist_kernel(const int* __restrict__ edge_dst, int* __restrict__ deg,
                            int E, int ET) {
  const int e = blockIdx.x * blockDim.x + threadIdx.x;
  if (e < ET) {
    const int d = (e < E) ? edge_dst[e] : (e - E);
    atomicAdd(&deg[d], 1);
  }
}

__global__ __launch_bounds__(1024) void scan_kernel(const int* __restrict__ deg,
                                                    int* __restrict__ row_ptr, int n) {
  __shared__ int wsum[16];
  __shared__ int carry_s;
  const int t = threadIdx.x, lane = t & 63, w = t >> 6;
  if (t == 0) {
    carry_s = 0;
    row_ptr[0] = 0;
  }
  __syncthreads();
  for (int base = 0; base < n; base += 1024) {
    const int idx = base + t;
    int x = (idx < n) ? deg[idx] : 0;
#pragma unroll
    for (int off = 1; off < 64; off <<= 1) {
      int y = __shfl_up(x, off);
      if (lane >= off) x += y;
    }
    if (lane == 63) wsum[w] = x;
    __syncthreads();
    if (w == 0) {
      int s = (lane < 16) ? wsum[lane] : 0;
#pragma unroll
      for (int off = 1; off < 16; off <<= 1) {
        int y = __shfl_up(s, off);
        if (lane >= off) s += y;
      }
      if (lane < 16) wsum[lane] = s;
    }
    __syncthreads();
    const int woff = (w > 0) ? wsum[w - 1] : 0;
    const int incl = carry_s + woff + x;
    if (idx < n) row_ptr[idx + 1] = incl;
    __syncthreads();
    if (t == 1023) carry_s = incl;
    __syncthreads();
  }
}

__global__ void scatter_kernel(const int* __restrict__ edge_src,
                               const int* __restrict__ edge_dst,
                               const int* __restrict__ row_ptr,
                               int* __restrict__ cursor,
                               int* __restrict__ ssrc, int E, int ET) {
  const int e = blockIdx.x * blockDim.x + threadIdx.x;
  if (e < ET) {
    int d, s;
    if (e < E) {
      d = edge_dst[e];
      s = edge_src[e];
    } else {
      d = s = e - E;
    }
    const int pos = atomicAdd(&cursor[d], 1);
    ssrc[row_ptr[d] + pos] = s;
  }
}

// ---------------------------------------------------------------------------
// Softmax stats: thread per (dst,head). Pass1: m. Pass2: p=exp(e-m) stored,
// S accumulated; store 1/(S+eps).
// ---------------------------------------------------------------------------
__global__ __launch_bounds__(256) void stats_kernel(
    const float* __restrict__ al_s4, const float* __restrict__ al_d4,
    const int* __restrict__ row_ptr, const int* __restrict__ ssrc,
    float* __restrict__ p4, float* __restrict__ rs4, int n) {
  const int gid = blockIdx.x * blockDim.x + threadIdx.x;
  if (gid >= n * HEADS) return;
  const int d = gid >> 2;
  const int hd = gid & 3;
  const int start = row_ptr[d];
  const int end = row_ptr[d + 1];
  const float ald = al_d4[gid];

  float m = -INFINITY;
  for (int i = start; i < end; ++i) {
    const int s = ssrc[i];
    float e = al_s4[s * HEADS + hd] + ald;
    e = (e > 0.f) ? e : NEG_SLOPE * e;
    m = fmaxf(m, e);
  }
  float S = 0.f;
  for (int i = start; i < end; ++i) {
    const int s = ssrc[i];
    float e = al_s4[s * HEADS + hd] + ald;
    e = (e > 0.f) ? e : NEG_SLOPE * e;
    const float p = __expf(e - m);
    p4[i * HEADS + hd] = p;
    S += p;
  }
  rs4[gid] = 1.f / (S + 1e-16f);
}

// ---------------------------------------------------------------------------
// Aggregate: block = 128 thr (2 waves) per dst. Lane covers channel pair.
// acc += p * h16[src]; epilogue: acc * (1/S) + bias.
// ---------------------------------------------------------------------------
template <typename OT>
__global__ __launch_bounds__(128) void agg_kernel(
    const _Float16* __restrict__ h16, const float* __restrict__ p4,
    const float* __restrict__ rs4, const int* __restrict__ row_ptr,
    const int* __restrict__ ssrc, const float* __restrict__ bias,
    OT* __restrict__ out, int n) {
  const int d = blockIdx.x;
  const int t = threadIdx.x;
  const int c0 = t * 2;
  const int head = c0 >> 6;
  const int start = row_ptr[d];
  const int end = row_ptr[d + 1];

  float acc0 = 0.f, acc1 = 0.f;
  int i = start;
  for (; i + 1 < end; i += 2) {
    const int s0 = ssrc[i];
    const int s1 = ssrc[i + 1];
    const float pa = p4[i * HEADS + head];
    const float pb = p4[(i + 1) * HEADS + head];
    const f16x2 h0 = *reinterpret_cast<const f16x2*>(&h16[(size_t)s0 * HID + c0]);
    const f16x2 h1 = *reinterpret_cast<const f16x2*>(&h16[(size_t)s1 * HID + c0]);
    acc0 += pa * (float)h0.x + pb * (float)h1.x;
    acc1 += pa * (float)h0.y + pb * (float)h1.y;
  }
  if (i < end) {
    const int s0 = ssrc[i];
    const float pa = p4[i * HEADS + head];
    const f16x2 h0 = *reinterpret_cast<const f16x2*>(&h16[(size_t)s0 * HID + c0]);
    acc0 += pa * (float)h0.x;
    acc1 += pa * (float)h0.y;
  }
  const float r = rs4[d * HEADS + head];
  out[(size_t)d * HID + c0] = (OT)(acc0 * r + bias[c0]);
  out[(size_t)d * HID + c0 + 1] = (OT)(acc1 * r + bias[c0 + 1]);
}

// ---------------------------------------------------------------------------
extern "C" void kernel_launch(void* const* d_in, const int* in_sizes, int n_in,
                              void* d_out, int out_size, void* d_ws, size_t ws_size,
                              hipStream_t stream) {
  const float* x   = (const float*)d_in[0];
  const int* esrc  = (const int*)d_in[1];
  const int* edst  = (const int*)d_in[2];
  const float* W1  = (const float*)d_in[3];
  const float* a1s = (const float*)d_in[4];
  const float* a1d = (const float*)d_in[5];
  const float* b1  = (const float*)d_in[6];
  const float* W2  = (const float*)d_in[7];
  const float* a2s = (const float*)d_in[8];
  const float* a2d = (const float*)d_in[9];
  const float* b2  = (const float*)d_in[10];
  float* out = (float*)d_out;

  const int N = in_sizes[0] / IN_DIM;  // 20000
  const int E = in_sizes[1];           // 320000
  const int ET = E + N;

  char* ws = (char*)d_ws;
  _Float16* h16 = (_Float16*)ws;  ws += (size_t)N * HID * sizeof(_Float16);
  _Float16* x116 = (_Float16*)ws; ws += (size_t)N * HID * sizeof(_Float16);
  float* al_s4 = (float*)ws;      ws += (size_t)N * HEADS * sizeof(float);
  float* al_d4 = (float*)ws;      ws += (size_t)N * HEADS * sizeof(float);
  float* rs4 = (float*)ws;        ws += (size_t)N * HEADS * sizeof(float);
  int* row_ptr = (int*)ws;        ws += (size_t)(N + 1) * sizeof(int);
  int* deg = (int*)ws;            ws += (size_t)N * sizeof(int);
  int* cursor = (int*)ws;         ws += (size_t)N * sizeof(int);
  int* ssrc = (int*)ws;           ws += (size_t)ET * sizeof(int);
  ws = (char*)(((size_t)ws + 15) & ~(size_t)15);
  float* p4 = (float*)ws;         ws += (size_t)ET * HEADS * sizeof(float);
  _Float16* W1t = (_Float16*)ws;  ws += (size_t)HID * IN_DIM * sizeof(_Float16);
  _Float16* W2t = (_Float16*)ws;  ws += (size_t)HID * HID * sizeof(_Float16);

  hipMemsetAsync(deg, 0, (size_t)N * sizeof(int), stream);
  hipMemsetAsync(cursor, 0, (size_t)N * sizeof(int), stream);

  const int thr = 256;
  wconv_kernel<<<(IN_DIM * HID + thr - 1) / thr, thr, 0, stream>>>(W1, W1t, IN_DIM);
  wconv_kernel<<<(HID * HID + thr - 1) / thr, thr, 0, stream>>>(W2, W2t, HID);

  hist_kernel<<<(ET + thr - 1) / thr, thr, 0, stream>>>(edst, deg, E, ET);
  scan_kernel<<<1, 1024, 0, stream>>>(deg, row_ptr, N);
  scatter_kernel<<<(ET + thr - 1) / thr, thr, 0, stream>>>(esrc, edst, row_ptr,
                                                           cursor, ssrc, E, ET);

  dim3 ggrid((N + BM - 1) / BM, HID / BN);
  const int sgrid = (N * HEADS + thr - 1) / thr;
  // ---- layer 1
  gemm_f16<false><<<ggrid, 256, 0, stream>>>(x, W1t, h16, N, IN_DIM);
  alpha_kernel<<<N, 256, 0, stream>>>(h16, a1s, a1d, al_s4, al_d4, N);
  stats_kernel<<<sgrid, thr, 0, stream>>>(al_s4, al_d4, row_ptr, ssrc, p4, rs4, N);
  agg_kernel<_Float16><<<N, 128, 0, stream>>>(h16, p4, rs4, row_ptr, ssrc, b1,
                                              x116, N);
  // ---- layer 2
  gemm_f16<true><<<ggrid, 256, 0, stream>>>(x116, W2t, h16, N, HID);
  alpha_kernel<<<N, 256, 0, stream>>>(h16, a2s, a2d, al_s4, al_d4, N);
  stats_kernel<<<sgrid, thr, 0, stream>>>(al_s4, al_d4, row_ptr, ssrc, p4, rs4, N);
  agg_kernel<float><<<N, 128, 0, stream>>>(h16, p4, rs4, row_ptr, ssrc, b2,
                                           out, N);
}

// Round 4
// 246.793 us; speedup vs baseline: 1.9153x; 1.0058x over previous
//
#include <hip/hip_runtime.h>
#include <math.h>

#define HEADS 4
#define CH 64
#define HID 256
#define IN_DIM 768
#define NEG_SLOPE 0.2f

typedef _Float16 f16x8 __attribute__((ext_vector_type(8)));
typedef _Float16 f16x4 __attribute__((ext_vector_type(4)));
typedef float f32x4 __attribute__((ext_vector_type(4)));

// ---------------------------------------------------------------------------
// W [K][256] fp32 -> Wt [256][K] fp16
// ---------------------------------------------------------------------------
__global__ void wconv_kernel(const float* __restrict__ W, _Float16* __restrict__ Wt,
                             int K) {
  const int idx = blockIdx.x * blockDim.x + threadIdx.x;
  if (idx < K * HID) {
    const int k = idx >> 8;
    const int n = idx & 255;
    Wt[(size_t)n * K + k] = (_Float16)W[idx];
  }
}

// ---------------------------------------------------------------------------
// GEMM: C16[M,256] = A[M,K] x Bt[256,K]^T  via mfma_f32_16x16x32_f16
// 512 thr = 8 waves (2 row x 4 col), tile 128x128, BK=64.
// Reg-staged double-buffer; XOR-swizzled LDS (chunk ^= row&7), b128 conflict-free.
// ---------------------------------------------------------------------------
#define BM 128
#define BN 128
#define BK 64

template <bool AF16>
__global__ __launch_bounds__(512) void gemm_f16(
    const void* __restrict__ Av, const _Float16* __restrict__ Bt,
    _Float16* __restrict__ C, int M, int K) {
  __shared__ f16x8 As8[BM * 8];   // [row][chunk^], 16B chunks, 16KB
  __shared__ f16x8 Bs8[BN * 8];   // [col][chunk^], 16KB

  const int t = threadIdx.x;
  const int lane = t & 63;
  const int wid = t >> 6;
  const int wm = wid & 1;         // 2 row-groups of 64
  const int wn = wid >> 1;        // 4 col-groups of 32
  const int row0 = blockIdx.x * BM;
  const int col0 = blockIdx.y * BN;
  const int rl = lane & 15;
  const int qk = lane >> 4;

  f32x4 acc[4][2] = {};

  // staging regs
  float4 rf[2][2];   // AF32 path
  f16x8 ra[2];       // AF16 path
  f16x8 rb[2];

  const _Float16* A16 = (const _Float16*)Av;
  const float* A32 = (const float*)Av;

  auto loadA = [&](int kt) {
#pragma unroll
    for (int j = 0; j < 2; ++j) {
      const int idx = t + j * 512;          // 0..1023
      const int r = idx >> 3;
      const int q = idx & 7;
      const int grow = row0 + r;
      if (AF16) {
        ra[j] = (grow < M)
                    ? *reinterpret_cast<const f16x8*>(&A16[(size_t)grow * K + kt * BK + q * 8])
                    : (f16x8){};
      } else {
        if (grow < M) {
          const float* p = &A32[(size_t)grow * K + kt * BK + q * 8];
          rf[j][0] = *reinterpret_cast<const float4*>(p);
          rf[j][1] = *reinterpret_cast<const float4*>(p + 4);
        } else {
          rf[j][0] = make_float4(0.f, 0.f, 0.f, 0.f);
          rf[j][1] = make_float4(0.f, 0.f, 0.f, 0.f);
        }
      }
    }
  };
  auto loadB = [&](int kt) {
#pragma unroll
    for (int j = 0; j < 2; ++j) {
      const int idx = t + j * 512;
      const int c = idx >> 3;
      const int q = idx & 7;
      rb[j] = *reinterpret_cast<const f16x8*>(&Bt[(size_t)(col0 + c) * K + kt * BK + q * 8]);
    }
  };
  auto writeLDS = [&]() {
#pragma unroll
    for (int j = 0; j < 2; ++j) {
      const int idx = t + j * 512;
      const int r = idx >> 3;
      const int q = idx & 7;
      if (AF16) {
        As8[r * 8 + (q ^ (r & 7))] = ra[j];
      } else {
        const float4 u = rf[j][0], v = rf[j][1];
        f16x8 w = {(_Float16)u.x, (_Float16)u.y, (_Float16)u.z, (_Float16)u.w,
                   (_Float16)v.x, (_Float16)v.y, (_Float16)v.z, (_Float16)v.w};
        As8[r * 8 + (q ^ (r & 7))] = w;
      }
      Bs8[r * 8 + (q ^ (r & 7))] = rb[j];   // same idx mapping for B (c == r)
    }
  };

  const int NT = K / BK;
  loadA(0);
  loadB(0);
  writeLDS();
  __syncthreads();

  for (int kt = 0; kt < NT; ++kt) {
    const bool more = (kt + 1 < NT);
    if (more) {
      loadA(kt + 1);
      loadB(kt + 1);
    }
    // compute from LDS
#pragma unroll
    for (int ks = 0; ks < 2; ++ks) {
      f16x8 af[4], bf[2];
      const int qx = (qk + 4 * ks) ^ (rl & 7);
#pragma unroll
      for (int m = 0; m < 4; ++m)
        af[m] = As8[(wm * 64 + m * 16 + rl) * 8 + qx];
#pragma unroll
      for (int nn = 0; nn < 2; ++nn)
        bf[nn] = Bs8[(wn * 32 + nn * 16 + rl) * 8 + qx];
#pragma unroll
      for (int m = 0; m < 4; ++m)
#pragma unroll
        for (int nn = 0; nn < 2; ++nn)
          acc[m][nn] = __builtin_amdgcn_mfma_f32_16x16x32_f16(af[m], bf[nn],
                                                              acc[m][nn], 0, 0, 0);
    }
    if (more) {
      __syncthreads();
      writeLDS();
      __syncthreads();
    }
  }

  // epilogue: row=(lane>>4)*4+r, col=lane&15 within 16x16 frag
#pragma unroll
  for (int m = 0; m < 4; ++m) {
    const int gr0 = row0 + wm * 64 + m * 16 + qk * 4;
#pragma unroll
    for (int nn = 0; nn < 2; ++nn) {
      const int gc = col0 + wn * 32 + nn * 16 + rl;
#pragma unroll
      for (int r = 0; r < 4; ++r) {
        const int gr = gr0 + r;
        if (gr < M) C[(size_t)gr * HID + gc] = (_Float16)acc[m][nn][r];
      }
    }
  }
}

// ---------------------------------------------------------------------------
// Attention logits per node: al_s4[n*4+h] = <h16[n,h,:], a_src[h,:]>
// ---------------------------------------------------------------------------
__global__ __launch_bounds__(256) void alpha_kernel(
    const _Float16* __restrict__ h16, const float* __restrict__ a_src,
    const float* __restrict__ a_dst, float* __restrict__ al_s4,
    float* __restrict__ al_d4, int n) {
  const int node = blockIdx.x;
  const int hd = threadIdx.x >> 6;
  const int lane = threadIdx.x & 63;
  const float hv = (float)h16[(size_t)node * HID + hd * CH + lane];
  float vs = hv * a_src[hd * CH + lane];
  float vd = hv * a_dst[hd * CH + lane];
#pragma unroll
  for (int m = 32; m >= 1; m >>= 1) {
    vs += __shfl_xor(vs, m);
    vd += __shfl_xor(vd, m);
  }
  if (lane == 0) {
    al_s4[node * HEADS + hd] = vs;
    al_d4[node * HEADS + hd] = vd;
  }
}

// ---------------------------------------------------------------------------
// CSR build
// ---------------------------------------------------------------------------
__global__ void hist_kernel(const int* __restrict__ edge_dst, int* __restrict__ deg,
                            int E, int ET) {
  const int e = blockIdx.x * blockDim.x + threadIdx.x;
  if (e < ET) {
    const int d = (e < E) ? edge_dst[e] : (e - E);
    atomicAdd(&deg[d], 1);
  }
}

__global__ __launch_bounds__(1024) void scan_kernel(const int* __restrict__ deg,
                                                    int* __restrict__ row_ptr, int n) {
  __shared__ int wsum[16];
  __shared__ int carry_s;
  const int t = threadIdx.x, lane = t & 63, w = t >> 6;
  if (t == 0) {
    carry_s = 0;
    row_ptr[0] = 0;
  }
  __syncthreads();
  for (int base = 0; base < n; base += 1024) {
    const int idx = base + t;
    int x = (idx < n) ? deg[idx] : 0;
#pragma unroll
    for (int off = 1; off < 64; off <<= 1) {
      int y = __shfl_up(x, off);
      if (lane >= off) x += y;
    }
    if (lane == 63) wsum[w] = x;
    __syncthreads();
    if (w == 0) {
      int s = (lane < 16) ? wsum[lane] : 0;
#pragma unroll
      for (int off = 1; off < 16; off <<= 1) {
        int y = __shfl_up(s, off);
        if (lane >= off) s += y;
      }
      if (lane < 16) wsum[lane] = s;
    }
    __syncthreads();
    const int woff = (w > 0) ? wsum[w - 1] : 0;
    const int incl = carry_s + woff + x;
    if (idx < n) row_ptr[idx + 1] = incl;
    __syncthreads();
    if (t == 1023) carry_s = incl;
    __syncthreads();
  }
}

__global__ void scatter_kernel(const int* __restrict__ edge_src,
                               const int* __restrict__ edge_dst,
                               const int* __restrict__ row_ptr,
                               int* __restrict__ cursor,
                               int* __restrict__ ssrc, int* __restrict__ sdst,
                               int E, int ET) {
  const int e = blockIdx.x * blockDim.x + threadIdx.x;
  if (e < ET) {
    int d, s;
    if (e < E) {
      d = edge_dst[e];
      s = edge_src[e];
    } else {
      d = s = e - E;
    }
    const int pos = atomicAdd(&cursor[d], 1);
    ssrc[row_ptr[d] + pos] = s;
    sdst[row_ptr[d] + pos] = d;
  }
}

// ---------------------------------------------------------------------------
// Edge-parallel logits: e4[i] = leakyrelu(al_s4[src] + al_d4[dst]) (float4)
// ---------------------------------------------------------------------------
__global__ __launch_bounds__(256) void logits_kernel(
    const float* __restrict__ al_s4, const float* __restrict__ al_d4,
    const int* __restrict__ ssrc, const int* __restrict__ sdst,
    float4* __restrict__ e4, int ET) {
  const int i = blockIdx.x * blockDim.x + threadIdx.x;
  if (i >= ET) return;
  const int s = ssrc[i];
  const int d = sdst[i];
  const float4 as = *reinterpret_cast<const float4*>(&al_s4[s * 4]);
  const float4 ad = *reinterpret_cast<const float4*>(&al_d4[d * 4]);
  float4 e;
  e.x = as.x + ad.x; e.x = (e.x > 0.f) ? e.x : NEG_SLOPE * e.x;
  e.y = as.y + ad.y; e.y = (e.y > 0.f) ? e.y : NEG_SLOPE * e.y;
  e.z = as.z + ad.z; e.z = (e.z > 0.f) ? e.z : NEG_SLOPE * e.z;
  e.w = as.w + ad.w; e.w = (e.w > 0.f) ? e.w : NEG_SLOPE * e.w;
  e4[i] = e;
}

// ---------------------------------------------------------------------------
// Per-dst softmax stats over contiguous e4 segment: p4[i]=exp(e-m), rs4=1/S
// ---------------------------------------------------------------------------
__global__ __launch_bounds__(256) void stats2_kernel(
    const float4* __restrict__ e4, const int* __restrict__ row_ptr,
    float4* __restrict__ p4, float4* __restrict__ rs4, int n) {
  const int d = blockIdx.x * blockDim.x + threadIdx.x;
  if (d >= n) return;
  const int start = row_ptr[d];
  const int end = row_ptr[d + 1];
  float4 m = make_float4(-INFINITY, -INFINITY, -INFINITY, -INFINITY);
  for (int i = start; i < end; ++i) {
    const float4 v = e4[i];
    m.x = fmaxf(m.x, v.x); m.y = fmaxf(m.y, v.y);
    m.z = fmaxf(m.z, v.z); m.w = fmaxf(m.w, v.w);
  }
  float4 S = make_float4(0.f, 0.f, 0.f, 0.f);
  for (int i = start; i < end; ++i) {
    const float4 v = e4[i];
    float4 p;
    p.x = __expf(v.x - m.x); p.y = __expf(v.y - m.y);
    p.z = __expf(v.z - m.z); p.w = __expf(v.w - m.w);
    p4[i] = p;
    S.x += p.x; S.y += p.y; S.z += p.z; S.w += p.w;
  }
  float4 r;
  r.x = 1.f / (S.x + 1e-16f); r.y = 1.f / (S.y + 1e-16f);
  r.z = 1.f / (S.z + 1e-16f); r.w = 1.f / (S.w + 1e-16f);
  rs4[d] = r;
}

// ---------------------------------------------------------------------------
// Aggregate: wave per dst (4 dst/block). Lane holds 4 channels (f16x4 = 8B).
// ---------------------------------------------------------------------------
template <typename OT>
__global__ __launch_bounds__(256) void agg_kernel(
    const _Float16* __restrict__ h16, const float* __restrict__ p4f,
    const float* __restrict__ rs4f, const int* __restrict__ row_ptr,
    const int* __restrict__ ssrc, const float* __restrict__ bias,
    OT* __restrict__ out, int n) {
  const int d = blockIdx.x * 4 + (threadIdx.x >> 6);
  if (d >= n) return;
  const int lane = threadIdx.x & 63;
  const int head = lane >> 4;
  const int c0 = lane * 4;
  const int start = row_ptr[d];
  const int end = row_ptr[d + 1];

  float a0 = 0.f, a1 = 0.f, a2 = 0.f, a3 = 0.f;
  int i = start;
  for (; i + 1 < end; i += 2) {
    const int s0 = ssrc[i];
    const int s1 = ssrc[i + 1];
    const float pa = p4f[i * 4 + head];
    const float pb = p4f[(i + 1) * 4 + head];
    const f16x4 h0 = *reinterpret_cast<const f16x4*>(&h16[(size_t)s0 * HID + c0]);
    const f16x4 h1 = *reinterpret_cast<const f16x4*>(&h16[(size_t)s1 * HID + c0]);
    a0 += pa * (float)h0.x + pb * (float)h1.x;
    a1 += pa * (float)h0.y + pb * (float)h1.y;
    a2 += pa * (float)h0.z + pb * (float)h1.z;
    a3 += pa * (float)h0.w + pb * (float)h1.w;
  }
  if (i < end) {
    const int s0 = ssrc[i];
    const float pa = p4f[i * 4 + head];
    const f16x4 h0 = *reinterpret_cast<const f16x4*>(&h16[(size_t)s0 * HID + c0]);
    a0 += pa * (float)h0.x;
    a1 += pa * (float)h0.y;
    a2 += pa * (float)h0.z;
    a3 += pa * (float)h0.w;
  }
  const float r = rs4f[d * 4 + head];
  const float4 bv = *reinterpret_cast<const float4*>(&bias[c0]);
  if (sizeof(OT) == 2) {
    f16x4 o = {(_Float16)(a0 * r + bv.x), (_Float16)(a1 * r + bv.y),
               (_Float16)(a2 * r + bv.z), (_Float16)(a3 * r + bv.w)};
    *reinterpret_cast<f16x4*>(&((_Float16*)out)[(size_t)d * HID + c0]) = o;
  } else {
    float4 o = make_float4(a0 * r + bv.x, a1 * r + bv.y, a2 * r + bv.z,
                           a3 * r + bv.w);
    *reinterpret_cast<float4*>(&((float*)out)[(size_t)d * HID + c0]) = o;
  }
}

// ---------------------------------------------------------------------------
extern "C" void kernel_launch(void* const* d_in, const int* in_sizes, int n_in,
                              void* d_out, int out_size, void* d_ws, size_t ws_size,
                              hipStream_t stream) {
  const float* x   = (const float*)d_in[0];
  const int* esrc  = (const int*)d_in[1];
  const int* edst  = (const int*)d_in[2];
  const float* W1  = (const float*)d_in[3];
  const float* a1s = (const float*)d_in[4];
  const float* a1d = (const float*)d_in[5];
  const float* b1  = (const float*)d_in[6];
  const float* W2  = (const float*)d_in[7];
  const float* a2s = (const float*)d_in[8];
  const float* a2d = (const float*)d_in[9];
  const float* b2  = (const float*)d_in[10];
  float* out = (float*)d_out;

  const int N = in_sizes[0] / IN_DIM;  // 20000
  const int E = in_sizes[1];           // 320000
  const int ET = E + N;

  char* ws = (char*)d_ws;
  _Float16* h16 = (_Float16*)ws;  ws += (size_t)N * HID * sizeof(_Float16);
  _Float16* x116 = (_Float16*)ws; ws += (size_t)N * HID * sizeof(_Float16);
  float* al_s4 = (float*)ws;      ws += (size_t)N * HEADS * sizeof(float);
  float* al_d4 = (float*)ws;      ws += (size_t)N * HEADS * sizeof(float);
  float* rs4 = (float*)ws;        ws += (size_t)N * HEADS * sizeof(float);
  int* row_ptr = (int*)ws;        ws += (size_t)(N + 1) * sizeof(int);
  int* deg = (int*)ws;            ws += (size_t)N * sizeof(int);
  int* cursor = (int*)ws;         ws += (size_t)N * sizeof(int);
  int* ssrc = (int*)ws;           ws += (size_t)ET * sizeof(int);
  int* sdst = (int*)ws;           ws += (size_t)ET * sizeof(int);
  ws = (char*)(((size_t)ws + 15) & ~(size_t)15);
  float4* e4 = (float4*)ws;       ws += (size_t)ET * sizeof(float4);
  float4* p4 = (float4*)ws;       ws += (size_t)ET * sizeof(float4);
  _Float16* W1t = (_Float16*)ws;  ws += (size_t)HID * IN_DIM * sizeof(_Float16);
  _Float16* W2t = (_Float16*)ws;  ws += (size_t)HID * HID * sizeof(_Float16);

  hipMemsetAsync(deg, 0, (size_t)N * sizeof(int), stream);
  hipMemsetAsync(cursor, 0, (size_t)N * sizeof(int), stream);

  const int thr = 256;
  wconv_kernel<<<(IN_DIM * HID + thr - 1) / thr, thr, 0, stream>>>(W1, W1t, IN_DIM);
  wconv_kernel<<<(HID * HID + thr - 1) / thr, thr, 0, stream>>>(W2, W2t, HID);

  hist_kernel<<<(ET + thr - 1) / thr, thr, 0, stream>>>(edst, deg, E, ET);
  scan_kernel<<<1, 1024, 0, stream>>>(deg, row_ptr, N);
  scatter_kernel<<<(ET + thr - 1) / thr, thr, 0, stream>>>(esrc, edst, row_ptr,
                                                           cursor, ssrc, sdst, E, ET);

  dim3 ggrid((N + BM - 1) / BM, HID / BN);
  const int egrid = (ET + thr - 1) / thr;
  const int ngrid = (N + thr - 1) / thr;
  const int agrid = (N + 3) / 4;

  // ---- layer 1
  gemm_f16<false><<<ggrid, 512, 0, stream>>>(x, W1t, h16, N, IN_DIM);
  alpha_kernel<<<N, 256, 0, stream>>>(h16, a1s, a1d, al_s4, al_d4, N);
  logits_kernel<<<egrid, thr, 0, stream>>>(al_s4, al_d4, ssrc, sdst, e4, ET);
  stats2_kernel<<<ngrid, thr, 0, stream>>>(e4, row_ptr, p4, (float4*)rs4, N);
  agg_kernel<_Float16><<<agrid, 256, 0, stream>>>(h16, (const float*)p4, rs4,
                                                  row_ptr, ssrc, b1, x116, N);
  // ---- layer 2
  gemm_f16<true><<<ggrid, 512, 0, stream>>>(x116, W2t, h16, N, HID);
  alpha_kernel<<<N, 256, 0, stream>>>(h16, a2s, a2d, al_s4, al_d4, N);
  logits_kernel<<<egrid, thr, 0, stream>>>(al_s4, al_d4, ssrc, sdst, e4, ET);
  stats2_kernel<<<ngrid, thr, 0, stream>>>(e4, row_ptr, p4, (float4*)rs4, N);
  agg_kernel<float><<<agrid, 256, 0, stream>>>(h16, (const float*)p4, rs4,
                                               row_ptr, ssrc, b2, out, N);
}

// Round 5
// 187.944 us; speedup vs baseline: 2.5150x; 1.3131x over previous
//
#include <hip/hip_runtime.h>
#include <math.h>

#define HEADS 4
#define CH 64
#define HID 256
#define IN_DIM 768
#define NEG_SLOPE 0.2f

typedef _Float16 f16x8 __attribute__((ext_vector_type(8)));
typedef _Float16 f16x4 __attribute__((ext_vector_type(4)));
typedef float f32x4 __attribute__((ext_vector_type(4)));

// ---------------------------------------------------------------------------
// W [K][256] fp32 -> Wt [256][K] fp16
// ---------------------------------------------------------------------------
__global__ void wconv_kernel(const float* __restrict__ W, _Float16* __restrict__ Wt,
                             int K) {
  const int idx = blockIdx.x * blockDim.x + threadIdx.x;
  if (idx < K * HID) {
    const int k = idx >> 8;
    const int n = idx & 255;
    Wt[(size_t)n * K + k] = (_Float16)W[idx];
  }
}

// ---------------------------------------------------------------------------
// GEMM + fused attention logits.
// C16[M,256] = A[M,K] x Bt[256,K]^T  via mfma_f32_16x16x32_f16
// 512 thr = 8 waves (2 row x 4 col), tile 128x128, BK=64, reg-staged dbuf,
// XOR-swizzled LDS. Epilogue: al_s/al_d for this block's 2 heads from fp32 acc.
// ---------------------------------------------------------------------------
#define BM 128
#define BN 128
#define BK 64

template <bool AF16>
__global__ __launch_bounds__(512) void gemm_f16(
    const void* __restrict__ Av, const _Float16* __restrict__ Bt,
    _Float16* __restrict__ C, const float* __restrict__ a_src,
    const float* __restrict__ a_dst, float* __restrict__ al_s4,
    float* __restrict__ al_d4, int M, int K) {
  __shared__ f16x8 As8[BM * 8];   // 16KB
  __shared__ f16x8 Bs8[BN * 8];   // 16KB

  const int t = threadIdx.x;
  const int lane = t & 63;
  const int wid = t >> 6;
  const int wm = wid & 1;
  const int wn = wid >> 1;
  const int row0 = blockIdx.x * BM;
  const int col0 = blockIdx.y * BN;
  const int rl = lane & 15;
  const int qk = lane >> 4;

  f32x4 acc[4][2] = {};

  float4 rf[2][2];
  f16x8 ra[2];
  f16x8 rb[2];

  const _Float16* A16 = (const _Float16*)Av;
  const float* A32 = (const float*)Av;

  auto loadA = [&](int kt) {
#pragma unroll
    for (int j = 0; j < 2; ++j) {
      const int idx = t + j * 512;
      const int r = idx >> 3;
      const int q = idx & 7;
      const int grow = row0 + r;
      if (AF16) {
        ra[j] = (grow < M)
                    ? *reinterpret_cast<const f16x8*>(&A16[(size_t)grow * K + kt * BK + q * 8])
                    : (f16x8){};
      } else {
        if (grow < M) {
          const float* p = &A32[(size_t)grow * K + kt * BK + q * 8];
          rf[j][0] = *reinterpret_cast<const float4*>(p);
          rf[j][1] = *reinterpret_cast<const float4*>(p + 4);
        } else {
          rf[j][0] = make_float4(0.f, 0.f, 0.f, 0.f);
          rf[j][1] = make_float4(0.f, 0.f, 0.f, 0.f);
        }
      }
    }
  };
  auto loadB = [&](int kt) {
#pragma unroll
    for (int j = 0; j < 2; ++j) {
      const int idx = t + j * 512;
      const int c = idx >> 3;
      const int q = idx & 7;
      rb[j] = *reinterpret_cast<const f16x8*>(&Bt[(size_t)(col0 + c) * K + kt * BK + q * 8]);
    }
  };
  auto writeLDS = [&]() {
#pragma unroll
    for (int j = 0; j < 2; ++j) {
      const int idx = t + j * 512;
      const int r = idx >> 3;
      const int q = idx & 7;
      if (AF16) {
        As8[r * 8 + (q ^ (r & 7))] = ra[j];
      } else {
        const float4 u = rf[j][0], v = rf[j][1];
        f16x8 w = {(_Float16)u.x, (_Float16)u.y, (_Float16)u.z, (_Float16)u.w,
                   (_Float16)v.x, (_Float16)v.y, (_Float16)v.z, (_Float16)v.w};
        As8[r * 8 + (q ^ (r & 7))] = w;
      }
      Bs8[r * 8 + (q ^ (r & 7))] = rb[j];
    }
  };

  const int NT = K / BK;
  loadA(0);
  loadB(0);
  writeLDS();
  __syncthreads();

  for (int kt = 0; kt < NT; ++kt) {
    const bool more = (kt + 1 < NT);
    if (more) {
      loadA(kt + 1);
      loadB(kt + 1);
    }
#pragma unroll
    for (int ks = 0; ks < 2; ++ks) {
      f16x8 af[4], bf[2];
      const int qx = (qk + 4 * ks) ^ (rl & 7);
#pragma unroll
      for (int m = 0; m < 4; ++m)
        af[m] = As8[(wm * 64 + m * 16 + rl) * 8 + qx];
#pragma unroll
      for (int nn = 0; nn < 2; ++nn)
        bf[nn] = Bs8[(wn * 32 + nn * 16 + rl) * 8 + qx];
#pragma unroll
      for (int m = 0; m < 4; ++m)
#pragma unroll
        for (int nn = 0; nn < 2; ++nn)
          acc[m][nn] = __builtin_amdgcn_mfma_f32_16x16x32_f16(af[m], bf[nn],
                                                              acc[m][nn], 0, 0, 0);
    }
    if (more) {
      __syncthreads();
      writeLDS();
      __syncthreads();
    }
  }

  // ---- C store (frag: row=(lane>>4)*4+r, col=lane&15)
#pragma unroll
  for (int m = 0; m < 4; ++m) {
    const int gr0 = row0 + wm * 64 + m * 16 + qk * 4;
#pragma unroll
    for (int nn = 0; nn < 2; ++nn) {
      const int gc = col0 + wn * 32 + nn * 16 + rl;
#pragma unroll
      for (int r = 0; r < 4; ++r) {
        const int gr = gr0 + r;
        if (gr < M) C[(size_t)gr * HID + gc] = (_Float16)acc[m][nn][r];
      }
    }
  }

  // ---- fused alpha: this block covers heads {col0/64, col0/64+1} fully.
  __syncthreads();                       // LDS reuse
  float* als = reinterpret_cast<float*>(As8);  // [128][2] for s, then d
  float* ald = als + 256;
  als[t < 512 ? t : 0] = 0.f;            // 512 threads zero 512 floats
  __syncthreads();

  const int head_l = wn >> 1;            // 0/1 within block
  const int hglob = (col0 >> 6) + head_l;
  const int ch0 = (wn & 1) * 32 + rl;    // channel within head (nn=0)
  const float as0 = a_src[hglob * CH + ch0];
  const float as1 = a_src[hglob * CH + ch0 + 16];
  const float ad0 = a_dst[hglob * CH + ch0];
  const float ad1 = a_dst[hglob * CH + ch0 + 16];
#pragma unroll
  for (int m = 0; m < 4; ++m) {
#pragma unroll
    for (int r = 0; r < 4; ++r) {
      float vs = acc[m][0][r] * as0 + acc[m][1][r] * as1;
      float vd = acc[m][0][r] * ad0 + acc[m][1][r] * ad1;
#pragma unroll
      for (int msk = 8; msk >= 1; msk >>= 1) {
        vs += __shfl_xor(vs, msk);
        vd += __shfl_xor(vd, msk);
      }
      if (rl == 0) {
        const int row = wm * 64 + m * 16 + qk * 4 + r;
        atomicAdd(&als[row * 2 + head_l], vs);
        atomicAdd(&ald[row * 2 + head_l], vd);
      }
    }
  }
  __syncthreads();
  if (t < 256) {
    const int row = t >> 1;
    const int hl = t & 1;
    const int grow = row0 + row;
    if (grow < M) {
      al_s4[grow * HEADS + (col0 >> 6) + hl] = als[row * 2 + hl];
      al_d4[grow * HEADS + (col0 >> 6) + hl] = ald[row * 2 + hl];
    }
  }
}

// ---------------------------------------------------------------------------
// CSR build
// ---------------------------------------------------------------------------
__global__ void hist_kernel(const int* __restrict__ edge_dst, int* __restrict__ deg,
                            int E, int ET) {
  const int e = blockIdx.x * blockDim.x + threadIdx.x;
  if (e < ET) {
    const int d = (e < E) ? edge_dst[e] : (e - E);
    atomicAdd(&deg[d], 1);
  }
}

// x4-vectorized single-block scan (n % 4 == 0 assumed; guarded otherwise)
__global__ __launch_bounds__(1024) void scan_kernel(const int* __restrict__ deg,
                                                    int* __restrict__ row_ptr, int n) {
  __shared__ int wsum[16];
  __shared__ int carry_s;
  const int t = threadIdx.x, lane = t & 63, w = t >> 6;
  if (t == 0) {
    carry_s = 0;
    row_ptr[0] = 0;
  }
  __syncthreads();
  for (int base = 0; base < n; base += 4096) {
    const int i0 = base + t * 4;
    int4 v = make_int4(0, 0, 0, 0);
    if (i0 < n) v = *reinterpret_cast<const int4*>(&deg[i0]);
    const int s0 = v.x, s1 = s0 + v.y, s2 = s1 + v.z, s3 = s2 + v.w;
    int x = s3;
#pragma unroll
    for (int off = 1; off < 64; off <<= 1) {
      int y = __shfl_up(x, off);
      if (lane >= off) x += y;
    }
    if (lane == 63) wsum[w] = x;
    __syncthreads();
    if (w == 0) {
      int s = (lane < 16) ? wsum[lane] : 0;
#pragma unroll
      for (int off = 1; off < 16; off <<= 1) {
        int y = __shfl_up(s, off);
        if (lane >= off) s += y;
      }
      if (lane < 16) wsum[lane] = s;
    }
    __syncthreads();
    const int woff = (w > 0) ? wsum[w - 1] : 0;
    const int pre = carry_s + woff + x - s3;   // exclusive base for this thread
    if (i0 < n) {
      row_ptr[i0 + 1] = pre + s0;
      row_ptr[i0 + 2] = pre + s1;
      row_ptr[i0 + 3] = pre + s2;
      row_ptr[i0 + 4] = pre + s3;
    }
    __syncthreads();
    if (t == 1023) carry_s = pre + s3;
    __syncthreads();
  }
}

// scatter + layer-1 logits fused (runs after GEMM1/alpha)
__global__ void scatter_kernel(const int* __restrict__ edge_src,
                               const int* __restrict__ edge_dst,
                               const int* __restrict__ row_ptr,
                               int* __restrict__ cursor,
                               int* __restrict__ ssrc, int* __restrict__ sdst,
                               const float* __restrict__ al_s4,
                               const float* __restrict__ al_d4,
                               float4* __restrict__ e4, int E, int ET) {
  const int e = blockIdx.x * blockDim.x + threadIdx.x;
  if (e < ET) {
    int d, s;
    if (e < E) {
      d = edge_dst[e];
      s = edge_src[e];
    } else {
      d = s = e - E;
    }
    const int pos = row_ptr[d] + atomicAdd(&cursor[d], 1);
    ssrc[pos] = s;
    sdst[pos] = d;
    const float4 as = *reinterpret_cast<const float4*>(&al_s4[s * 4]);
    const float4 ad = *reinterpret_cast<const float4*>(&al_d4[d * 4]);
    float4 ev;
    ev.x = as.x + ad.x; ev.x = (ev.x > 0.f) ? ev.x : NEG_SLOPE * ev.x;
    ev.y = as.y + ad.y; ev.y = (ev.y > 0.f) ? ev.y : NEG_SLOPE * ev.y;
    ev.z = as.z + ad.z; ev.z = (ev.z > 0.f) ? ev.z : NEG_SLOPE * ev.z;
    ev.w = as.w + ad.w; ev.w = (ev.w > 0.f) ? ev.w : NEG_SLOPE * ev.w;
    e4[pos] = ev;
  }
}

// layer-2 logits (CSR order already built)
__global__ __launch_bounds__(256) void logits_kernel(
    const float* __restrict__ al_s4, const float* __restrict__ al_d4,
    const int* __restrict__ ssrc, const int* __restrict__ sdst,
    float4* __restrict__ e4, int ET) {
  const int i = blockIdx.x * blockDim.x + threadIdx.x;
  if (i >= ET) return;
  const int s = ssrc[i];
  const int d = sdst[i];
  const float4 as = *reinterpret_cast<const float4*>(&al_s4[s * 4]);
  const float4 ad = *reinterpret_cast<const float4*>(&al_d4[d * 4]);
  float4 ev;
  ev.x = as.x + ad.x; ev.x = (ev.x > 0.f) ? ev.x : NEG_SLOPE * ev.x;
  ev.y = as.y + ad.y; ev.y = (ev.y > 0.f) ? ev.y : NEG_SLOPE * ev.y;
  ev.z = as.z + ad.z; ev.z = (ev.z > 0.f) ? ev.z : NEG_SLOPE * ev.z;
  ev.w = as.w + ad.w; ev.w = (ev.w > 0.f) ? ev.w : NEG_SLOPE * ev.w;
  e4[i] = ev;
}

// ---------------------------------------------------------------------------
// Aggregate with fused softmax stats. Wave per dst (4 dst/block).
// Phase 1: wave-parallel per-head max+sum over the segment (e4, 16B/lane).
// Phase 2: channel loop, p = exp(e - m) inline, acc += p * h16[src].
// ---------------------------------------------------------------------------
template <typename OT>
__global__ __launch_bounds__(256) void agg_kernel(
    const _Float16* __restrict__ h16, const float* __restrict__ e4f,
    const int* __restrict__ row_ptr, const int* __restrict__ ssrc,
    const float* __restrict__ bias, OT* __restrict__ out, int n) {
  const int d = blockIdx.x * 4 + (threadIdx.x >> 6);
  if (d >= n) return;
  const int lane = threadIdx.x & 63;
  const int start = row_ptr[d];
  const int end = row_ptr[d + 1];

  // phase 1
  float4 mv = make_float4(-INFINITY, -INFINITY, -INFINITY, -INFINITY);
  for (int i = start + lane; i < end; i += 64) {
    const float4 v = *reinterpret_cast<const float4*>(&e4f[i * 4]);
    mv.x = fmaxf(mv.x, v.x); mv.y = fmaxf(mv.y, v.y);
    mv.z = fmaxf(mv.z, v.z); mv.w = fmaxf(mv.w, v.w);
  }
#pragma unroll
  for (int msk = 32; msk >= 1; msk >>= 1) {
    mv.x = fmaxf(mv.x, __shfl_xor(mv.x, msk));
    mv.y = fmaxf(mv.y, __shfl_xor(mv.y, msk));
    mv.z = fmaxf(mv.z, __shfl_xor(mv.z, msk));
    mv.w = fmaxf(mv.w, __shfl_xor(mv.w, msk));
  }
  float4 Sv = make_float4(0.f, 0.f, 0.f, 0.f);
  for (int i = start + lane; i < end; i += 64) {
    const float4 v = *reinterpret_cast<const float4*>(&e4f[i * 4]);
    Sv.x += __expf(v.x - mv.x); Sv.y += __expf(v.y - mv.y);
    Sv.z += __expf(v.z - mv.z); Sv.w += __expf(v.w - mv.w);
  }
#pragma unroll
  for (int msk = 32; msk >= 1; msk >>= 1) {
    Sv.x += __shfl_xor(Sv.x, msk);
    Sv.y += __shfl_xor(Sv.y, msk);
    Sv.z += __shfl_xor(Sv.z, msk);
    Sv.w += __shfl_xor(Sv.w, msk);
  }
  const int head = lane >> 4;
  const float m_h = (head == 0) ? mv.x : (head == 1) ? mv.y : (head == 2) ? mv.z : mv.w;
  const float S_h = (head == 0) ? Sv.x : (head == 1) ? Sv.y : (head == 2) ? Sv.z : Sv.w;
  const float r_h = 1.f / (S_h + 1e-16f);

  // phase 2
  const int c0 = lane * 4;
  float a0 = 0.f, a1 = 0.f, a2 = 0.f, a3 = 0.f;
  int i = start;
  for (; i + 1 < end; i += 2) {
    const int s0 = ssrc[i];
    const int s1 = ssrc[i + 1];
    const float pa = __expf(e4f[i * 4 + head] - m_h);
    const float pb = __expf(e4f[(i + 1) * 4 + head] - m_h);
    const f16x4 h0 = *reinterpret_cast<const f16x4*>(&h16[(size_t)s0 * HID + c0]);
    const f16x4 h1 = *reinterpret_cast<const f16x4*>(&h16[(size_t)s1 * HID + c0]);
    a0 += pa * (float)h0.x + pb * (float)h1.x;
    a1 += pa * (float)h0.y + pb * (float)h1.y;
    a2 += pa * (float)h0.z + pb * (float)h1.z;
    a3 += pa * (float)h0.w + pb * (float)h1.w;
  }
  if (i < end) {
    const int s0 = ssrc[i];
    const float pa = __expf(e4f[i * 4 + head] - m_h);
    const f16x4 h0 = *reinterpret_cast<const f16x4*>(&h16[(size_t)s0 * HID + c0]);
    a0 += pa * (float)h0.x;
    a1 += pa * (float)h0.y;
    a2 += pa * (float)h0.z;
    a3 += pa * (float)h0.w;
  }
  const float4 bv = *reinterpret_cast<const float4*>(&bias[c0]);
  if (sizeof(OT) == 2) {
    f16x4 o = {(_Float16)(a0 * r_h + bv.x), (_Float16)(a1 * r_h + bv.y),
               (_Float16)(a2 * r_h + bv.z), (_Float16)(a3 * r_h + bv.w)};
    *reinterpret_cast<f16x4*>(&((_Float16*)out)[(size_t)d * HID + c0]) = o;
  } else {
    float4 o = make_float4(a0 * r_h + bv.x, a1 * r_h + bv.y, a2 * r_h + bv.z,
                           a3 * r_h + bv.w);
    *reinterpret_cast<float4*>(&((float*)out)[(size_t)d * HID + c0]) = o;
  }
}

// ---------------------------------------------------------------------------
static inline char* align16(char* p) {
  return (char*)(((size_t)p + 15) & ~(size_t)15);
}

extern "C" void kernel_launch(void* const* d_in, const int* in_sizes, int n_in,
                              void* d_out, int out_size, void* d_ws, size_t ws_size,
                              hipStream_t stream) {
  const float* x   = (const float*)d_in[0];
  const int* esrc  = (const int*)d_in[1];
  const int* edst  = (const int*)d_in[2];
  const float* W1  = (const float*)d_in[3];
  const float* a1s = (const float*)d_in[4];
  const float* a1d = (const float*)d_in[5];
  const float* b1  = (const float*)d_in[6];
  const float* W2  = (const float*)d_in[7];
  const float* a2s = (const float*)d_in[8];
  const float* a2d = (const float*)d_in[9];
  const float* b2  = (const float*)d_in[10];
  float* out = (float*)d_out;

  const int N = in_sizes[0] / IN_DIM;  // 20000
  const int E = in_sizes[1];           // 320000
  const int ET = E + N;

  char* ws = (char*)d_ws;
  _Float16* h16 = (_Float16*)ws;  ws = align16(ws + (size_t)N * HID * 2);
  _Float16* x116 = (_Float16*)ws; ws = align16(ws + (size_t)N * HID * 2);
  float* al_s4 = (float*)ws;      ws = align16(ws + (size_t)N * HEADS * 4);
  float* al_d4 = (float*)ws;      ws = align16(ws + (size_t)N * HEADS * 4);
  int* row_ptr = (int*)ws;        ws = align16(ws + (size_t)(N + 8) * 4);
  int* deg = (int*)ws;            ws = align16(ws + (size_t)(N + 8) * 4);
  int* cursor = (int*)ws;         ws = align16(ws + (size_t)N * 4);
  int* ssrc = (int*)ws;           ws = align16(ws + (size_t)ET * 4);
  int* sdst = (int*)ws;           ws = align16(ws + (size_t)ET * 4);
  float4* e4 = (float4*)ws;       ws = align16(ws + (size_t)ET * 16);
  _Float16* W1t = (_Float16*)ws;  ws = align16(ws + (size_t)HID * IN_DIM * 2);
  _Float16* W2t = (_Float16*)ws;  ws = align16(ws + (size_t)HID * HID * 2);

  hipMemsetAsync(deg, 0, (size_t)(N + 8) * 4, stream);
  hipMemsetAsync(cursor, 0, (size_t)N * 4, stream);

  const int thr = 256;
  wconv_kernel<<<(IN_DIM * HID + thr - 1) / thr, thr, 0, stream>>>(W1, W1t, IN_DIM);
  wconv_kernel<<<(HID * HID + thr - 1) / thr, thr, 0, stream>>>(W2, W2t, HID);

  hist_kernel<<<(ET + thr - 1) / thr, thr, 0, stream>>>(edst, deg, E, ET);
  scan_kernel<<<1, 1024, 0, stream>>>(deg, row_ptr, N);

  dim3 ggrid((N + BM - 1) / BM, HID / BN);
  const int egrid = (ET + thr - 1) / thr;
  const int agrid = (N + 3) / 4;

  // ---- layer 1
  gemm_f16<false><<<ggrid, 512, 0, stream>>>(x, W1t, h16, a1s, a1d,
                                             al_s4, al_d4, N, IN_DIM);
  scatter_kernel<<<egrid, thr, 0, stream>>>(esrc, edst, row_ptr, cursor, ssrc,
                                            sdst, al_s4, al_d4, e4, E, ET);
  agg_kernel<_Float16><<<agrid, 256, 0, stream>>>(h16, (const float*)e4, row_ptr,
                                                  ssrc, b1, x116, N);
  // ---- layer 2
  gemm_f16<true><<<ggrid, 512, 0, stream>>>(x116, W2t, h16, a2s, a2d,
                                            al_s4, al_d4, N, HID);
  logits_kernel<<<egrid, thr, 0, stream>>>(al_s4, al_d4, ssrc, sdst, e4, ET);
  agg_kernel<float><<<agrid, 256, 0, stream>>>(h16, (const float*)e4, row_ptr,
                                               ssrc, b2, out, N);
}

// Round 6
// 187.498 us; speedup vs baseline: 2.5209x; 1.0024x over previous
//
#include <hip/hip_runtime.h>
#include <math.h>

#define HEADS 4
#define CH 64
#define HID 256
#define IN_DIM 768
#define NEG_SLOPE 0.2f

typedef _Float16 f16x8 __attribute__((ext_vector_type(8)));
typedef _Float16 f16x4 __attribute__((ext_vector_type(4)));
typedef float f32x4 __attribute__((ext_vector_type(4)));

// ---------------------------------------------------------------------------
// prep: wconv W1 + wconv W2 + degree histogram, fused (block-range split)
// ---------------------------------------------------------------------------
#define G1 768   /* IN_DIM*HID/256 */
#define G2 256   /* HID*HID/256 */
__global__ void prep_kernel(const float* __restrict__ W1, _Float16* __restrict__ W1t,
                            const float* __restrict__ W2, _Float16* __restrict__ W2t,
                            const int* __restrict__ edge_dst, int* __restrict__ deg,
                            int E, int ET) {
  const int b = blockIdx.x;
  if (b < G1) {
    const int idx = b * 256 + threadIdx.x;
    const int k = idx >> 8, n = idx & 255;
    W1t[(size_t)n * IN_DIM + k] = (_Float16)W1[idx];
  } else if (b < G1 + G2) {
    const int idx = (b - G1) * 256 + threadIdx.x;
    const int k = idx >> 8, n = idx & 255;
    W2t[(size_t)n * HID + k] = (_Float16)W2[idx];
  } else {
    const int e = (b - G1 - G2) * 256 + threadIdx.x;
    if (e < ET) {
      const int d = (e < E) ? edge_dst[e] : (e - E);
      atomicAdd(&deg[d], 1);
    }
  }
}

// ---------------------------------------------------------------------------
// GEMM + fused attention logits.
// C16[M,256] = A[M,K] x Bt[256,K]^T  via mfma_f32_16x16x32_f16
// 256 thr = 4 waves (1 row-group x 4 col-strips), tile 64x128, BK=64,
// reg-staged dbuf, XOR-swizzled LDS. 4 blocks/CU for TLP latency hiding.
// Epilogue: al_s/al_d for the block's 2 heads from fp32 acc.
// ---------------------------------------------------------------------------
#define BM 64
#define BN 128
#define BK 64

template <bool AF16>
__global__ __launch_bounds__(256, 4) void gemm_f16(
    const void* __restrict__ Av, const _Float16* __restrict__ Bt,
    _Float16* __restrict__ C, const float* __restrict__ a_src,
    const float* __restrict__ a_dst, float* __restrict__ al_s4,
    float* __restrict__ al_d4, int M, int K) {
  __shared__ f16x8 As8[BM * 8];   // 8KB
  __shared__ f16x8 Bs8[BN * 8];   // 16KB

  const int t = threadIdx.x;
  const int lane = t & 63;
  const int wn = t >> 6;          // wave -> 32-col strip
  const int row0 = blockIdx.x * BM;
  const int col0 = blockIdx.y * BN;
  const int rl = lane & 15;
  const int qk = lane >> 4;

  f32x4 acc[4][2] = {};

  float4 rf[2][2];   // AF32 staging
  f16x8 ra[2];       // AF16 staging
  f16x8 rb[4];       // B staging

  const _Float16* A16 = (const _Float16*)Av;
  const float* A32 = (const float*)Av;

  const int arow = t >> 2;         // 0..63
  const int ac0 = (t & 3) * 2;     // A chunk base (2 chunks/thread)
  const int brow = t >> 1;         // 0..127
  const int bc0 = (t & 1) * 4;     // B chunk base (4 chunks/thread)

  auto loadA = [&](int kt) {
    const int grow = row0 + arow;
    if (AF16) {
#pragma unroll
      for (int c = 0; c < 2; ++c)
        ra[c] = (grow < M)
                    ? *reinterpret_cast<const f16x8*>(&A16[(size_t)grow * K + kt * BK + (ac0 + c) * 8])
                    : (f16x8){};
    } else {
#pragma unroll
      for (int c = 0; c < 2; ++c) {
        if (grow < M) {
          const float* p = &A32[(size_t)grow * K + kt * BK + (ac0 + c) * 8];
          rf[c][0] = *reinterpret_cast<const float4*>(p);
          rf[c][1] = *reinterpret_cast<const float4*>(p + 4);
        } else {
          rf[c][0] = make_float4(0.f, 0.f, 0.f, 0.f);
          rf[c][1] = make_float4(0.f, 0.f, 0.f, 0.f);
        }
      }
    }
  };
  auto loadB = [&](int kt) {
#pragma unroll
    for (int c = 0; c < 4; ++c)
      rb[c] = *reinterpret_cast<const f16x8*>(&Bt[(size_t)(col0 + brow) * K + kt * BK + (bc0 + c) * 8]);
  };
  auto writeLDS = [&]() {
#pragma unroll
    for (int c = 0; c < 2; ++c) {
      f16x8 w;
      if (AF16) {
        w = ra[c];
      } else {
        const float4 u = rf[c][0], v = rf[c][1];
        w = (f16x8){(_Float16)u.x, (_Float16)u.y, (_Float16)u.z, (_Float16)u.w,
                    (_Float16)v.x, (_Float16)v.y, (_Float16)v.z, (_Float16)v.w};
      }
      As8[arow * 8 + ((ac0 + c) ^ (arow & 7))] = w;
    }
#pragma unroll
    for (int c = 0; c < 4; ++c)
      Bs8[brow * 8 + ((bc0 + c) ^ (brow & 7))] = rb[c];
  };

  const int NT = K / BK;
  loadA(0);
  loadB(0);
  writeLDS();
  __syncthreads();

  for (int kt = 0; kt < NT; ++kt) {
    const bool more = (kt + 1 < NT);
    if (more) {
      loadA(kt + 1);
      loadB(kt + 1);
    }
#pragma unroll
    for (int ks = 0; ks < 2; ++ks) {
      f16x8 af[4], bf[2];
      const int qx = (qk + 4 * ks) ^ (rl & 7);
#pragma unroll
      for (int m = 0; m < 4; ++m)
        af[m] = As8[(m * 16 + rl) * 8 + qx];
#pragma unroll
      for (int nn = 0; nn < 2; ++nn)
        bf[nn] = Bs8[(wn * 32 + nn * 16 + rl) * 8 + qx];
#pragma unroll
      for (int m = 0; m < 4; ++m)
#pragma unroll
        for (int nn = 0; nn < 2; ++nn)
          acc[m][nn] = __builtin_amdgcn_mfma_f32_16x16x32_f16(af[m], bf[nn],
                                                              acc[m][nn], 0, 0, 0);
    }
    if (more) {
      __syncthreads();
      writeLDS();
      __syncthreads();
    }
  }

  // ---- C store (frag: row=(lane>>4)*4+r, col=lane&15)
#pragma unroll
  for (int m = 0; m < 4; ++m) {
    const int gr0 = row0 + m * 16 + qk * 4;
#pragma unroll
    for (int nn = 0; nn < 2; ++nn) {
      const int gc = col0 + wn * 32 + nn * 16 + rl;
#pragma unroll
      for (int r = 0; r < 4; ++r) {
        const int gr = gr0 + r;
        if (gr < M) C[(size_t)gr * HID + gc] = (_Float16)acc[m][nn][r];
      }
    }
  }

  // ---- fused alpha for the block's 2 heads (cols col0..col0+127)
  __syncthreads();                 // LDS reuse
  float* als = reinterpret_cast<float*>(As8);  // [64][2]
  float* ald = als + 128;                      // [64][2]
  als[t < 256 ? t : 0] = 0.f;      // 256 threads zero 256 floats
  __syncthreads();

  const int head_l = wn >> 1;                  // 0/1
  const int hglob = (col0 >> 6) + head_l;
  const int ch0 = (wn & 1) * 32 + rl;          // channel within head (nn=0)
  const float as0 = a_src[hglob * CH + ch0];
  const float as1 = a_src[hglob * CH + ch0 + 16];
  const float ad0 = a_dst[hglob * CH + ch0];
  const float ad1 = a_dst[hglob * CH + ch0 + 16];
#pragma unroll
  for (int m = 0; m < 4; ++m) {
#pragma unroll
    for (int r = 0; r < 4; ++r) {
      float vs = acc[m][0][r] * as0 + acc[m][1][r] * as1;
      float vd = acc[m][0][r] * ad0 + acc[m][1][r] * ad1;
#pragma unroll
      for (int msk = 8; msk >= 1; msk >>= 1) {
        vs += __shfl_xor(vs, msk);
        vd += __shfl_xor(vd, msk);
      }
      if (rl == 0) {
        const int row = m * 16 + qk * 4 + r;
        atomicAdd(&als[row * 2 + head_l], vs);
        atomicAdd(&ald[row * 2 + head_l], vd);
      }
    }
  }
  __syncthreads();
  if (t < 128) {
    const int row = t >> 1;
    const int hl = t & 1;
    const int grow = row0 + row;
    if (grow < M) {
      al_s4[grow * HEADS + (col0 >> 6) + hl] = als[row * 2 + hl];
      al_d4[grow * HEADS + (col0 >> 6) + hl] = ald[row * 2 + hl];
    }
  }
}

// ---------------------------------------------------------------------------
// x4-vectorized single-block scan
// ---------------------------------------------------------------------------
__global__ __launch_bounds__(1024) void scan_kernel(const int* __restrict__ deg,
                                                    int* __restrict__ row_ptr, int n) {
  __shared__ int wsum[16];
  __shared__ int carry_s;
  const int t = threadIdx.x, lane = t & 63, w = t >> 6;
  if (t == 0) {
    carry_s = 0;
    row_ptr[0] = 0;
  }
  __syncthreads();
  for (int base = 0; base < n; base += 4096) {
    const int i0 = base + t * 4;
    int4 v = make_int4(0, 0, 0, 0);
    if (i0 < n) v = *reinterpret_cast<const int4*>(&deg[i0]);
    const int s0 = v.x, s1 = s0 + v.y, s2 = s1 + v.z, s3 = s2 + v.w;
    int x = s3;
#pragma unroll
    for (int off = 1; off < 64; off <<= 1) {
      int y = __shfl_up(x, off);
      if (lane >= off) x += y;
    }
    if (lane == 63) wsum[w] = x;
    __syncthreads();
    if (w == 0) {
      int s = (lane < 16) ? wsum[lane] : 0;
#pragma unroll
      for (int off = 1; off < 16; off <<= 1) {
        int y = __shfl_up(s, off);
        if (lane >= off) s += y;
      }
      if (lane < 16) wsum[lane] = s;
    }
    __syncthreads();
    const int woff = (w > 0) ? wsum[w - 1] : 0;
    const int pre = carry_s + woff + x - s3;
    if (i0 < n) {
      row_ptr[i0 + 1] = pre + s0;
      row_ptr[i0 + 2] = pre + s1;
      row_ptr[i0 + 3] = pre + s2;
      row_ptr[i0 + 4] = pre + s3;
    }
    __syncthreads();
    if (t == 1023) carry_s = pre + s3;
    __syncthreads();
  }
}

// ---------------------------------------------------------------------------
// scatter + layer-1 logits fused (after GEMM1)
// ---------------------------------------------------------------------------
__global__ void scatter_kernel(const int* __restrict__ edge_src,
                               const int* __restrict__ edge_dst,
                               const int* __restrict__ row_ptr,
                               int* __restrict__ cursor,
                               int* __restrict__ ssrc, int* __restrict__ sdst,
                               const float* __restrict__ al_s4,
                               const float* __restrict__ al_d4,
                               float4* __restrict__ e4, int E, int ET) {
  const int e = blockIdx.x * blockDim.x + threadIdx.x;
  if (e < ET) {
    int d, s;
    if (e < E) {
      d = edge_dst[e];
      s = edge_src[e];
    } else {
      d = s = e - E;
    }
    const int pos = row_ptr[d] + atomicAdd(&cursor[d], 1);
    ssrc[pos] = s;
    sdst[pos] = d;
    const float4 as = *reinterpret_cast<const float4*>(&al_s4[s * 4]);
    const float4 ad = *reinterpret_cast<const float4*>(&al_d4[d * 4]);
    float4 ev;
    ev.x = as.x + ad.x; ev.x = (ev.x > 0.f) ? ev.x : NEG_SLOPE * ev.x;
    ev.y = as.y + ad.y; ev.y = (ev.y > 0.f) ? ev.y : NEG_SLOPE * ev.y;
    ev.z = as.z + ad.z; ev.z = (ev.z > 0.f) ? ev.z : NEG_SLOPE * ev.z;
    ev.w = as.w + ad.w; ev.w = (ev.w > 0.f) ? ev.w : NEG_SLOPE * ev.w;
    e4[pos] = ev;
  }
}

// layer-2 logits (CSR order already built)
__global__ __launch_bounds__(256) void logits_kernel(
    const float* __restrict__ al_s4, const float* __restrict__ al_d4,
    const int* __restrict__ ssrc, const int* __restrict__ sdst,
    float4* __restrict__ e4, int ET) {
  const int i = blockIdx.x * blockDim.x + threadIdx.x;
  if (i >= ET) return;
  const int s = ssrc[i];
  const int d = sdst[i];
  const float4 as = *reinterpret_cast<const float4*>(&al_s4[s * 4]);
  const float4 ad = *reinterpret_cast<const float4*>(&al_d4[d * 4]);
  float4 ev;
  ev.x = as.x + ad.x; ev.x = (ev.x > 0.f) ? ev.x : NEG_SLOPE * ev.x;
  ev.y = as.y + ad.y; ev.y = (ev.y > 0.f) ? ev.y : NEG_SLOPE * ev.y;
  ev.z = as.z + ad.z; ev.z = (ev.z > 0.f) ? ev.z : NEG_SLOPE * ev.z;
  ev.w = as.w + ad.w; ev.w = (ev.w > 0.f) ? ev.w : NEG_SLOPE * ev.w;
  e4[i] = ev;
}

// ---------------------------------------------------------------------------
// Aggregate with fused softmax stats. Wave per dst (4 dst/block).
// ---------------------------------------------------------------------------
template <typename OT>
__global__ __launch_bounds__(256) void agg_kernel(
    const _Float16* __restrict__ h16, const float* __restrict__ e4f,
    const int* __restrict__ row_ptr, const int* __restrict__ ssrc,
    const float* __restrict__ bias, OT* __restrict__ out, int n) {
  const int d = blockIdx.x * 4 + (threadIdx.x >> 6);
  if (d >= n) return;
  const int lane = threadIdx.x & 63;
  const int start = row_ptr[d];
  const int end = row_ptr[d + 1];

  // phase 1: per-head max & sum (wave-parallel over segment)
  float4 mv = make_float4(-INFINITY, -INFINITY, -INFINITY, -INFINITY);
  for (int i = start + lane; i < end; i += 64) {
    const float4 v = *reinterpret_cast<const float4*>(&e4f[i * 4]);
    mv.x = fmaxf(mv.x, v.x); mv.y = fmaxf(mv.y, v.y);
    mv.z = fmaxf(mv.z, v.z); mv.w = fmaxf(mv.w, v.w);
  }
#pragma unroll
  for (int msk = 32; msk >= 1; msk >>= 1) {
    mv.x = fmaxf(mv.x, __shfl_xor(mv.x, msk));
    mv.y = fmaxf(mv.y, __shfl_xor(mv.y, msk));
    mv.z = fmaxf(mv.z, __shfl_xor(mv.z, msk));
    mv.w = fmaxf(mv.w, __shfl_xor(mv.w, msk));
  }
  float4 Sv = make_float4(0.f, 0.f, 0.f, 0.f);
  for (int i = start + lane; i < end; i += 64) {
    const float4 v = *reinterpret_cast<const float4*>(&e4f[i * 4]);
    Sv.x += __expf(v.x - mv.x); Sv.y += __expf(v.y - mv.y);
    Sv.z += __expf(v.z - mv.z); Sv.w += __expf(v.w - mv.w);
  }
#pragma unroll
  for (int msk = 32; msk >= 1; msk >>= 1) {
    Sv.x += __shfl_xor(Sv.x, msk);
    Sv.y += __shfl_xor(Sv.y, msk);
    Sv.z += __shfl_xor(Sv.z, msk);
    Sv.w += __shfl_xor(Sv.w, msk);
  }
  const int head = lane >> 4;
  const float m_h = (head == 0) ? mv.x : (head == 1) ? mv.y : (head == 2) ? mv.z : mv.w;
  const float S_h = (head == 0) ? Sv.x : (head == 1) ? Sv.y : (head == 2) ? Sv.z : Sv.w;
  const float r_h = 1.f / (S_h + 1e-16f);

  // phase 2: weighted gather
  const int c0 = lane * 4;
  float a0 = 0.f, a1 = 0.f, a2 = 0.f, a3 = 0.f;
  int i = start;
  for (; i + 1 < end; i += 2) {
    const int s0 = ssrc[i];
    const int s1 = ssrc[i + 1];
    const float pa = __expf(e4f[i * 4 + head] - m_h);
    const float pb = __expf(e4f[(i + 1) * 4 + head] - m_h);
    const f16x4 h0 = *reinterpret_cast<const f16x4*>(&h16[(size_t)s0 * HID + c0]);
    const f16x4 h1 = *reinterpret_cast<const f16x4*>(&h16[(size_t)s1 * HID + c0]);
    a0 += pa * (float)h0.x + pb * (float)h1.x;
    a1 += pa * (float)h0.y + pb * (float)h1.y;
    a2 += pa * (float)h0.z + pb * (float)h1.z;
    a3 += pa * (float)h0.w + pb * (float)h1.w;
  }
  if (i < end) {
    const int s0 = ssrc[i];
    const float pa = __expf(e4f[i * 4 + head] - m_h);
    const f16x4 h0 = *reinterpret_cast<const f16x4*>(&h16[(size_t)s0 * HID + c0]);
    a0 += pa * (float)h0.x;
    a1 += pa * (float)h0.y;
    a2 += pa * (float)h0.z;
    a3 += pa * (float)h0.w;
  }
  const float4 bv = *reinterpret_cast<const float4*>(&bias[c0]);
  if (sizeof(OT) == 2) {
    f16x4 o = {(_Float16)(a0 * r_h + bv.x), (_Float16)(a1 * r_h + bv.y),
               (_Float16)(a2 * r_h + bv.z), (_Float16)(a3 * r_h + bv.w)};
    *reinterpret_cast<f16x4*>(&((_Float16*)out)[(size_t)d * HID + c0]) = o;
  } else {
    float4 o = make_float4(a0 * r_h + bv.x, a1 * r_h + bv.y, a2 * r_h + bv.z,
                           a3 * r_h + bv.w);
    *reinterpret_cast<float4*>(&((float*)out)[(size_t)d * HID + c0]) = o;
  }
}

// ---------------------------------------------------------------------------
static inline char* align16(char* p) {
  return (char*)(((size_t)p + 15) & ~(size_t)15);
}

extern "C" void kernel_launch(void* const* d_in, const int* in_sizes, int n_in,
                              void* d_out, int out_size, void* d_ws, size_t ws_size,
                              hipStream_t stream) {
  const float* x   = (const float*)d_in[0];
  const int* esrc  = (const int*)d_in[1];
  const int* edst  = (const int*)d_in[2];
  const float* W1  = (const float*)d_in[3];
  const float* a1s = (const float*)d_in[4];
  const float* a1d = (const float*)d_in[5];
  const float* b1  = (const float*)d_in[6];
  const float* W2  = (const float*)d_in[7];
  const float* a2s = (const float*)d_in[8];
  const float* a2d = (const float*)d_in[9];
  const float* b2  = (const float*)d_in[10];
  float* out = (float*)d_out;

  const int N = in_sizes[0] / IN_DIM;  // 20000
  const int E = in_sizes[1];           // 320000
  const int ET = E + N;

  char* ws = (char*)d_ws;
  _Float16* h16 = (_Float16*)ws;  ws = align16(ws + (size_t)N * HID * 2);
  _Float16* x116 = (_Float16*)ws; ws = align16(ws + (size_t)N * HID * 2);
  float* al_s4 = (float*)ws;      ws = align16(ws + (size_t)N * HEADS * 4);
  float* al_d4 = (float*)ws;      ws = align16(ws + (size_t)N * HEADS * 4);
  int* row_ptr = (int*)ws;        ws = align16(ws + (size_t)(N + 8) * 4);
  int* deg = (int*)ws;            ws = align16(ws + (size_t)(N + 8) * 4);
  int* cursor = (int*)ws;         ws = align16(ws + (size_t)N * 4);
  int* ssrc = (int*)ws;           ws = align16(ws + (size_t)ET * 4);
  int* sdst = (int*)ws;           ws = align16(ws + (size_t)ET * 4);
  float4* e4 = (float4*)ws;       ws = align16(ws + (size_t)ET * 16);
  _Float16* W1t = (_Float16*)ws;  ws = align16(ws + (size_t)HID * IN_DIM * 2);
  _Float16* W2t = (_Float16*)ws;  ws = align16(ws + (size_t)HID * HID * 2);

  hipMemsetAsync(deg, 0, (size_t)(N + 8) * 4, stream);
  hipMemsetAsync(cursor, 0, (size_t)N * 4, stream);

  const int thr = 256;
  const int hgrid = (ET + thr - 1) / thr;
  prep_kernel<<<G1 + G2 + hgrid, thr, 0, stream>>>(W1, W1t, W2, W2t, edst, deg,
                                                   E, ET);
  scan_kernel<<<1, 1024, 0, stream>>>(deg, row_ptr, N);

  dim3 ggrid((N + BM - 1) / BM, HID / BN);
  const int egrid = (ET + thr - 1) / thr;
  const int agrid = (N + 3) / 4;

  // ---- layer 1
  gemm_f16<false><<<ggrid, 256, 0, stream>>>(x, W1t, h16, a1s, a1d,
                                             al_s4, al_d4, N, IN_DIM);
  scatter_kernel<<<egrid, thr, 0, stream>>>(esrc, edst, row_ptr, cursor, ssrc,
                                            sdst, al_s4, al_d4, e4, E, ET);
  agg_kernel<_Float16><<<agrid, 256, 0, stream>>>(h16, (const float*)e4, row_ptr,
                                                  ssrc, b1, x116, N);
  // ---- layer 2
  gemm_f16<true><<<ggrid, 256, 0, stream>>>(x116, W2t, h16, a2s, a2d,
                                            al_s4, al_d4, N, HID);
  logits_kernel<<<egrid, thr, 0, stream>>>(al_s4, al_d4, ssrc, sdst, e4, ET);
  agg_kernel<float><<<agrid, 256, 0, stream>>>(h16, (const float*)e4, row_ptr,
                                               ssrc, b2, out, N);
}